// Round 9
// baseline (156.605 us; speedup 1.0000x reference)
//
#include <hip/hip_runtime.h>
#include <hip/hip_bf16.h>
#include <math.h>

#define T_LEN 2048
#define BATCH 4
#define DMODEL 256
#define MROWS (BATCH*T_LEN)
#define PLANE (MROWS*DMODEL)
#define CH_L 32
#define NCH  (T_LEN/CH_L)          // 64
#define SUMSZ (BATCH*NCH*DMODEL)   // 65536
#define MSLOT (DMODEL*DMODEL)      // 65536

typedef __bf16 bf16;
typedef __bf16 bf16x8 __attribute__((ext_vector_type(8)));
typedef float  f32x4  __attribute__((ext_vector_type(4)));
typedef unsigned short u16;
typedef u16 u16x8 __attribute__((ext_vector_type(8)));
typedef unsigned int u32;

#define MFMA(a,b,c) __builtin_amdgcn_mfma_f32_16x16x32_bf16(a, b, c, 0, 0, 0)

__device__ __forceinline__ void split_bf16(float x, bf16& hi, bf16& lo) {
    hi = (bf16)x;
    lo = (bf16)(x - (float)hi);
}

__device__ __forceinline__ float bflo(u32 v) { union { u16 u; bf16 b; } c; c.u = (u16)(v & 0xffffu); return (float)c.b; }
__device__ __forceinline__ float bfhi(u32 v) { union { u16 u; bf16 b; } c; c.u = (u16)(v >> 16); return (float)c.b; }

__device__ __forceinline__ void split8(const float* p, bf16x8& h, bf16x8& l) {
    f32x4 a = *(const f32x4*)p;
    f32x4 b = *(const f32x4*)(p + 4);
    #pragma unroll
    for (int e = 0; e < 4; ++e) {
        bf16 hh, ll;
        split_bf16(a[e], hh, ll); h[e] = hh; l[e] = ll;
        split_bf16(b[e], hh, ll); h[4+e] = hh; l[4+e] = ll;
    }
}

// fast transcendentals (hardware v_exp_f32 based)
__device__ __forceinline__ float tanh_fast(float z) {
    z = fminf(fmaxf(z, -15.f), 15.f);
    float e = __expf(2.f * z);
    return (e - 1.f) / (e + 1.f);
}
__device__ __forceinline__ float nsoftplus_fast(float y) {   // -softplus(y)
    return -(fmaxf(y, 0.f) + __logf(1.f + __expf(-fabsf(y))));
}
__device__ __forceinline__ float sigmoid_fast(float y) {
    return 1.f / (1.f + __expf(-y));
}

#define GLD16(SRC, DST) __builtin_amdgcn_global_load_lds( \
    (const __attribute__((address_space(1))) void*)(SRC), \
    (__attribute__((address_space(3))) void*)(DST), 16, 0, 0)

// ---------------- split x into bf16 hi/lo planes (grid = PLANE/2048 = 1024)
__global__ __launch_bounds__(256) void split_x(const float* __restrict__ x,
                                               bf16* __restrict__ xh,
                                               bf16* __restrict__ xl) {
    int i = (blockIdx.x*256 + threadIdx.x) * 8;
    f32x4 a = *(const f32x4*)(x + i);
    f32x4 b = *(const f32x4*)(x + i + 4);
    bf16x8 h, l;
    #pragma unroll
    for (int e = 0; e < 4; ++e) {
        bf16 hh, ll;
        split_bf16(a[e], hh, ll); h[e] = hh;   l[e] = ll;
        split_bf16(b[e], hh, ll); h[4+e] = hh; l[4+e] = ll;
    }
    *(bf16x8*)(xh + i) = h;
    *(bf16x8*)(xl + i) = l;
}

// ---------------- pack weights (coalesced LDS transpose): WcatT[n][k] hi/lo, n in [0,1536)
__global__ __launch_bounds__(256) void pack_w(const float* __restrict__ Wq,
                                              const float* __restrict__ Wk,
                                              const float* __restrict__ Wv,
                                              const float* __restrict__ Wg,
                                              bf16* __restrict__ WhT,
                                              bf16* __restrict__ WlT) {
    __shared__ float tile[16][260];   // [n-local][k]
    const int tid = threadIdx.x;
    const int n0 = blockIdx.x * 16;
    const float* src; int nb, nw;
    if (n0 < 256)      { src = Wq; nb = n0;       nw = 256; }
    else if (n0 < 512) { src = Wk; nb = n0 - 256; nw = 256; }
    else if (n0 < 768) { src = Wv; nb = n0 - 512; nw = 256; }
    else               { src = Wg; nb = n0 - 768; nw = 768; }
    const int j = tid & 15, kk = tid >> 4;
    #pragma unroll
    for (int r = 0; r < 16; ++r) {
        int k = r*16 + kk;
        tile[j][k] = src[(size_t)k*nw + nb + j];
    }
    __syncthreads();
    #pragma unroll
    for (int r = 0; r < 16; ++r) {
        float v = tile[r][tid];
        bf16 h, l; split_bf16(v, h, l);
        WhT[(size_t)(n0 + r)*256 + tid] = h;
        WlT[(size_t)(n0 + r)*256 + tid] = l;
    }
}

// ---------------- fused projection GEMM: no LDS/barriers; 2-deep register pipeline
// pinned with sched_barrier(0) so loads for bank k+1 stay in flight under bank k's MFMAs.
__global__ __launch_bounds__(256, 2) void proj_gemm(
    const bf16* __restrict__ xh, const bf16* __restrict__ xl,
    const bf16* __restrict__ WhT, const bf16* __restrict__ WlT,
    const float* __restrict__ bq, const float* __restrict__ bk, const float* __restrict__ bv,
    const float* __restrict__ bg, const float* __restrict__ input_bias,
    float* __restrict__ qP, float* __restrict__ kP, float* __restrict__ vP,
    float* __restrict__ liP, float* __restrict__ lfP, float* __restrict__ soP)
{
    const int tid = threadIdx.x;
    const int w = tid >> 6, l = tid & 63;
    const int wr = w >> 1, wc = w & 1;
    const int m0 = blockIdx.x * 128;
    const int n0 = blockIdx.y * 128;
    const int lr = l & 15, lk = l >> 4;

    const bf16 *ahp[4], *alp[4], *bhp[4], *blp[4];
    #pragma unroll
    for (int mi = 0; mi < 4; ++mi) {
        size_t ro = (size_t)(m0 + wr*64 + mi*16 + lr)*256 + lk*8;
        ahp[mi] = xh + ro; alp[mi] = xl + ro;
    }
    #pragma unroll
    for (int ni = 0; ni < 4; ++ni) {
        size_t co = (size_t)(n0 + wc*64 + ni*16 + lr)*256 + lk*8;
        bhp[ni] = WhT + co; blp[ni] = WlT + co;
    }

    f32x4 acc[4][4] = {};
    bf16x8 a0h[4], a0l[4], b0h[4], b0l[4];
    bf16x8 a1h[4], a1l[4], b1h[4], b1l[4];

    #define LOADF(AH, AL, BH, BL, OFF) { \
        _Pragma("unroll") \
        for (int mi = 0; mi < 4; ++mi) { \
            AH[mi] = *(const bf16x8*)(ahp[mi] + (OFF)); \
            AL[mi] = *(const bf16x8*)(alp[mi] + (OFF)); } \
        _Pragma("unroll") \
        for (int ni = 0; ni < 4; ++ni) { \
            BH[ni] = *(const bf16x8*)(bhp[ni] + (OFF)); \
            BL[ni] = *(const bf16x8*)(blp[ni] + (OFF)); } }

    #define MFMAS(AH, AL, BH, BL) { \
        _Pragma("unroll") \
        for (int ni = 0; ni < 4; ++ni) \
            _Pragma("unroll") \
            for (int mi = 0; mi < 4; ++mi) { \
                acc[mi][ni] = MFMA(AH[mi], BH[ni], acc[mi][ni]); \
                acc[mi][ni] = MFMA(AL[mi], BH[ni], acc[mi][ni]); \
                acc[mi][ni] = MFMA(AH[mi], BL[ni], acc[mi][ni]); } }

    #define SB __builtin_amdgcn_sched_barrier(0);

    LOADF(a0h, a0l, b0h, b0l, 0)   SB
    LOADF(a1h, a1l, b1h, b1l, 32)  SB  MFMAS(a0h, a0l, b0h, b0l)  SB
    LOADF(a0h, a0l, b0h, b0l, 64)  SB  MFMAS(a1h, a1l, b1h, b1l)  SB
    LOADF(a1h, a1l, b1h, b1l, 96)  SB  MFMAS(a0h, a0l, b0h, b0l)  SB
    LOADF(a0h, a0l, b0h, b0l, 128) SB  MFMAS(a1h, a1l, b1h, b1l)  SB
    LOADF(a1h, a1l, b1h, b1l, 160) SB  MFMAS(a0h, a0l, b0h, b0l)  SB
    LOADF(a0h, a0l, b0h, b0l, 192) SB  MFMAS(a1h, a1l, b1h, b1l)  SB
    LOADF(a1h, a1l, b1h, b1l, 224) SB  MFMAS(a0h, a0l, b0h, b0l)  SB
    MFMAS(a1h, a1l, b1h, b1l)

    #undef LOADF
    #undef MFMAS
    #undef SB

    const int seg = n0 >> 8;   // 0=q 1=k 2=v 3=i 4=f 5=o (uniform per wg)
    #pragma unroll
    for (int mi = 0; mi < 4; ++mi) {
        #pragma unroll
        for (int ni = 0; ni < 4; ++ni) {
            int gcol = n0 + wc*64 + ni*16 + lr;
            int c = gcol & 255;
            #pragma unroll
            for (int r = 0; r < 4; ++r) {
                int grow = m0 + wr*64 + mi*16 + lk*4 + r;
                float val = acc[mi][ni][r];
                size_t o = (size_t)grow*256 + c;
                if (seg == 0)      qP[o] = val + bq[c];
                else if (seg == 1) kP[o] = (val + bk[c]) * 0.0625f;
                else if (seg == 2) vP[o] = val + bv[c];
                else if (seg == 3) { float y = val + bg[c] + input_bias[c];
                                     liP[o] = 10.0f * tanh_fast(y * 0.1f); }
                else if (seg == 4) { float y = val + bg[256 + c];
                                     lfP[o] = nsoftplus_fast(y); }
                else               { float y = val + bg[512 + c];
                                     soP[o] = sigmoid_fast(y); }
            }
        }
    }
}

// ---------------- fused chunk summary + Delta-M: per (b,c): C/mu/Bn (per dim) and
// DM[b,c] = Bhat_mu^T K (256x256, MFMA) -> bf16, with Bhat in LOCAL mu-scale.
__global__ __launch_bounds__(256) void s2_dm(
    const float* __restrict__ kP, const float* __restrict__ vP,
    const float* __restrict__ liP, const float* __restrict__ lfP,
    float* __restrict__ Csum, float* __restrict__ Mu, float* __restrict__ Bn,
    bf16* __restrict__ DM)
{
    __shared__ bf16 BTh[DMODEL][40], BTl[DMODEL][40];
    __shared__ bf16 KTh[DMODEL][40], KTl[DMODEL][40];
    const int tid = threadIdx.x;
    const int w = tid >> 6, l = tid & 63;
    const int b = blockIdx.x >> 6, c = blockIdx.x & 63;
    const size_t pb = ((size_t)b*T_LEN + (size_t)c*CH_L)*DMODEL;

    {
        float C = 0.f, mu = -3e38f;
        float val[CH_L];
        #pragma unroll
        for (int s = 0; s < CH_L; ++s) {
            size_t o = pb + (size_t)s*DMODEL + tid;
            C += lfP[o];
            val[s] = liP[o] - C;
            mu = fmaxf(mu, val[s]);
        }
        float bn = 0.f;
        #pragma unroll
        for (int s = 0; s < CH_L; ++s) {
            size_t o = pb + (size_t)s*DMODEL + tid;
            float e = __expf(val[s] - mu);
            float kv = kP[o];
            bn += e * kv;
            float bv = e * vP[o];
            bf16 h, lo; split_bf16(bv, h, lo);
            BTh[tid][s] = h; BTl[tid][s] = lo;
            bf16 kh, kl; split_bf16(kv, kh, kl);
            KTh[tid][s] = kh; KTl[tid][s] = kl;
        }
        size_t so = ((size_t)b*NCH + c)*DMODEL + tid;
        Csum[so] = C; Mu[so] = mu; Bn[so] = bn;
    }
    __syncthreads();

    const int lr = l & 15, lk = l >> 4;
    bf16x8 Ah[4], Al[4];
    #pragma unroll
    for (int it = 0; it < 4; ++it) {
        int row = w*64 + it*16 + lr;
        Ah[it] = *(const bf16x8*)&BTh[row][lk*8];
        Al[it] = *(const bf16x8*)&BTl[row][lk*8];
    }
    bf16* DMc = DM + (size_t)((size_t)b*NCH + c)*MSLOT;
    #pragma unroll
    for (int jt = 0; jt < 16; ++jt) {
        int jcol = jt*16 + lr;
        bf16x8 bh = *(const bf16x8*)&KTh[jcol][lk*8];
        bf16x8 bl = *(const bf16x8*)&KTl[jcol][lk*8];
        #pragma unroll
        for (int it = 0; it < 4; ++it) {
            f32x4 a = {0.f,0.f,0.f,0.f};
            a = MFMA(Ah[it], bh, a);
            a = MFMA(Al[it], bh, a);
            a = MFMA(Ah[it], bl, a);
            #pragma unroll
            for (int r = 0; r < 4; ++r)
                DMc[(size_t)(w*64 + it*16 + lk*4 + r)*DMODEL + jcol] = (bf16)a[r];
        }
    }
}

// ---------------- sequential compose of (m,n) boundary states across 64 chunks (tiny)
__global__ __launch_bounds__(256) void chunk_compose(
    const float* __restrict__ Csum, const float* __restrict__ Mu, const float* __restrict__ Bn,
    float* __restrict__ mIn, float* __restrict__ nIn, float* __restrict__ Th,
    float* __restrict__ Dd, float* __restrict__ Ee)
{
    const int b = blockIdx.x;
    const int j = threadIdx.x;
    float m = 0.f, n = 0.f;
    for (int c = 0; c < NCH; ++c) {
        size_t o = ((size_t)b*NCH + c)*DMODEL + j;
        mIn[o] = m; nIn[o] = n;
        float cs = Csum[o], mu = Mu[o], bn = Bn[o];
        float th = fmaxf(m, mu);
        Th[o] = th;
        float emu = __expf(mu - th);
        Dd[o] = __expf(m - th);
        Ee[o] = emu;
        n = __expf(m - th)*n + emu*bn;
        m = cs + th;
    }
}

// ---------------- compose M across chunks per (b,i,j); bf16 in/out, fp32 accumulate.
// DM stored in mu-scale; rescale to theta-scale via Ee when accumulating.
__global__ __launch_bounds__(256) void s3_compose(
    const float* __restrict__ Dd, const float* __restrict__ Ee, bf16* __restrict__ DM)
{
    const int b = blockIdx.x >> 8, i = blockIdx.x & 255;
    const int j = threadIdx.x;
    float acc = 0.f;
    const size_t base = ((size_t)b*NCH)*MSLOT + (size_t)i*DMODEL + j;
    for (int c = 0; c < NCH; ++c) {
        size_t a = base + (size_t)c*MSLOT;
        float dm = (float)DM[a];
        if (c > 0) DM[a] = (bf16)acc;
        size_t sx = ((size_t)b*NCH + c)*DMODEL + i;
        acc = Dd[sx]*acc + Ee[sx]*dm;
    }
}

// ---------------- per-chunk output + fused RMSNorm:
// H = F1*(Q Mprev^T) + Bt*(Gm^T Bhat); h = sigma(o)*H/denom; out = h/rms * scale
__global__ __launch_bounds__(256) void s4_chunk(
    const float* __restrict__ qP, const float* __restrict__ kP, const float* __restrict__ vP,
    const float* __restrict__ liP, const float* __restrict__ lfP, const float* __restrict__ soP,
    const float* __restrict__ mIn, const float* __restrict__ nIn, const float* __restrict__ Th,
    const bf16* __restrict__ DM, const float* __restrict__ norm_scale,
    float* __restrict__ out)
{
    __shared__ float Kf[CH_L][268];
    __shared__ float Qf[CH_L][268];       // aliased as Hout in the epilogue
    __shared__ float Pbuf[CH_L][260];     // aliased as packed scales
    __shared__ bf16 BTh[DMODEL][40];
    __shared__ float GT[CH_L][44];
    __shared__ float denoms[CH_L];

    const int tid = threadIdx.x;
    const int w = tid >> 6, l = tid & 63;
    const int b = blockIdx.x >> 6;
    const int c = blockIdx.x & 63;
    const size_t pb = ((size_t)b*T_LEN + (size_t)c*CH_L)*DMODEL;

    // phase 0: stage K,Q fp32 rows into LDS (completes under phase 1)
    #pragma unroll
    for (int r8 = 0; r8 < 8; ++r8) {
        int row = w*8 + r8;
        GLD16(kP + pb + (size_t)row*DMODEL + l*4, &Kf[row][l*4]);
        GLD16(qP + pb + (size_t)row*DMODEL + l*4, &Qf[row][l*4]);
    }

    // phase 1: per-dim recurrences (thread = dim)
    const int i = tid;
    const size_t cbx = ((size_t)b*NCH + c)*DMODEL + i;
    const float thL = Th[cbx];
    const float mI = mIn[cbx];
    float th_arr[CH_L];
    {
        float C = 0.f, mu = -3e38f, n = nIn[cbx], thp = mI;
        #pragma unroll
        for (int t = 0; t < CH_L; ++t) {
            size_t o = pb + (size_t)t*DMODEL + i;
            float lf = lfP[o], li = liP[o], kv = kP[o], qv = qP[o], vv = vP[o];
            C += lf;
            float vlc = li - C;
            mu = fmaxf(mu, vlc);
            float tht = fmaxf(mI, mu);
            th_arr[t] = tht;
            float f = __expf(thp - tht);
            float iv = __expf(vlc - tht);
            n = f*n + iv*kv;
            thp = tht;
            Pbuf[t][i] = n * qv;
            BTh[i][t] = (bf16)(__expf(vlc - thL) * vv);
        }
    }
    __syncthreads();

    // phase 2: denominators
    #pragma unroll
    for (int r = 0; r < 8; ++r) {
        int t = w*8 + r;
        f32x4 pv = *(const f32x4*)&Pbuf[t][l*4];
        float s = pv[0]+pv[1]+pv[2]+pv[3];
        #pragma unroll
        for (int sh = 32; sh; sh >>= 1) s += __shfl_xor(s, sh);
        if (l == 0) denoms[t] = fmaxf(fabsf(s), 1e-6f);
    }
    __syncthreads();

    // phase 3a: packed scales (F1, Bt) -> alias over Pbuf
    u32 (*scl)[260] = (u32(*)[260])Pbuf;
    #pragma unroll
    for (int t = 0; t < CH_L; ++t) {
        float F1 = __expf(mI - th_arr[t]);
        float Bt = __expf(thL - th_arr[t]);
        union { bf16 b; u16 u; } a1, a2; a1.b = (bf16)F1; a2.b = (bf16)Bt;
        scl[t][i] = (u32)a1.u | ((u32)a2.u << 16);
    }
    // phase 3b: G = K Q^T, one 16x16 tile per wave, masked write transposed
    {
        const int srow = (w & 1)*16, tcol = (w >> 1)*16;
        const int lr = l & 15, lk2 = l >> 4;
        f32x4 g = {0.f,0.f,0.f,0.f};
        #pragma unroll
        for (int ks = 0; ks < 8; ++ks) {
            bf16x8 ah, al, bh, bl;
            split8(&Kf[srow + lr][ks*32 + lk2*8], ah, al);
            split8(&Qf[tcol + lr][ks*32 + lk2*8], bh, bl);
            g = MFMA(ah, bh, g);
            g = MFMA(al, bh, g);
            g = MFMA(ah, bl, g);
        }
        #pragma unroll
        for (int r = 0; r < 4; ++r) {
            int s = srow + lk2*4 + r, t = tcol + lr;
            GT[t][s] = (s <= t) ? g[r] : 0.f;
        }
    }
    __syncthreads();

    // phase 4: output GEMMs. wave -> (t-half tt, 8 i-tiles)
    const int tt = w & 1;
    const int lr = l & 15, lk2 = l >> 4;
    const int trow = tt*16 + lr;
    f32x4 acc_a[8], acc_b[8];

    {   // intra: Gm^T Bhat  (K-dim = 32 = chunk)
        bf16x8 gh, gl;
        split8(&GT[trow][lk2*8], gh, gl);
        #pragma unroll
        for (int it = 0; it < 8; ++it) {
            int irow = ((w>>1)*8 + it)*16 + lr;
            bf16x8 bb = *(const bf16x8*)&BTh[irow][lk2*8];
            f32x4 a = {0.f,0.f,0.f,0.f};
            a = MFMA(gh, bb, a);
            a = MFMA(gl, bb, a);
            acc_a[it] = a;
        }
    }
    #pragma unroll
    for (int it = 0; it < 8; ++it) acc_b[it] = (f32x4){0.f,0.f,0.f,0.f};
    if (c > 0) {   // inter: Q Mprev^T, Mprev streamed bf16 from global
        const u16* Mbase = (const u16*)DM + (size_t)((size_t)b*NCH + c)*MSLOT;
        #pragma unroll
        for (int ks = 0; ks < 8; ++ks) {
            bf16x8 qh, ql;
            split8(&Qf[trow][ks*32 + lk2*8], qh, ql);
            #pragma unroll
            for (int it = 0; it < 8; ++it) {
                int irow = ((w>>1)*8 + it)*16 + lr;
                union { u16x8 u; bf16x8 h; } M8;
                M8.u = *(const u16x8*)(Mbase + (size_t)irow*DMODEL + ks*32 + lk2*8);
                f32x4 a = acc_b[it];
                a = MFMA(qh, M8.h, a);
                a = MFMA(ql, M8.h, a);
                acc_b[it] = a;
            }
        }
    }
    // epilogue part 1: combine into pre-norm h, park in LDS (alias Qf after all reads done)
    __syncthreads();
    float* Hout = &Qf[0][0];             // [32][268]
    #pragma unroll
    for (int it = 0; it < 8; ++it) {
        int icol = ((w>>1)*8 + it)*16 + lr;
        #pragma unroll
        for (int r = 0; r < 4; ++r) {
            int t = tt*16 + lk2*4 + r;
            u32 sc = scl[t][icol];
            float h = bflo(sc)*acc_b[it][r] + bfhi(sc)*acc_a[it][r];
            size_t o = pb + (size_t)t*DMODEL + icol;
            Hout[t*268 + icol] = soP[o] * h / denoms[t];
        }
    }
    __syncthreads();
    // epilogue part 2: fused RMSNorm (wave w owns rows w*8..w*8+7), coalesced stores
    #pragma unroll
    for (int r = 0; r < 8; ++r) {
        int t = w*8 + r;
        f32x4 hv = *(const f32x4*)&Hout[t*268 + l*4];
        float ss = hv[0]*hv[0] + hv[1]*hv[1] + hv[2]*hv[2] + hv[3]*hv[3];
        #pragma unroll
        for (int sh = 32; sh; sh >>= 1) ss += __shfl_xor(ss, sh);
        float rinv = rsqrtf(ss * (1.0f/256.0f) + 1e-8f);
        f32x4 ns = *(const f32x4*)(norm_scale + l*4);
        f32x4 o4;
        #pragma unroll
        for (int e = 0; e < 4; ++e) o4[e] = hv[e] * rinv * ns[e];
        *(f32x4*)(out + pb + (size_t)t*DMODEL + l*4) = o4;
    }
}

extern "C" void kernel_launch(void* const* d_in, const int* in_sizes, int n_in,
                              void* d_out, int out_size, void* d_ws, size_t ws_size,
                              hipStream_t stream) {
    const float* x          = (const float*)d_in[0];
    const float* Wq         = (const float*)d_in[1];
    const float* bq         = (const float*)d_in[2];
    const float* Wk         = (const float*)d_in[3];
    const float* bk         = (const float*)d_in[4];
    const float* Wv         = (const float*)d_in[5];
    const float* bv         = (const float*)d_in[6];
    const float* Wg         = (const float*)d_in[7];
    const float* bg         = (const float*)d_in[8];
    const float* input_bias = (const float*)d_in[9];
    const float* norm_scale = (const float*)d_in[10];
    float* out = (float*)d_out;

    float* qP   = (float*)d_ws;
    float* kP   = qP  + PLANE;
    float* vP   = kP  + PLANE;
    float* liP  = vP  + PLANE;
    float* lfP  = liP + PLANE;
    float* soP  = lfP + PLANE;
    float* Csum = soP + PLANE;
    float* Mu   = Csum + SUMSZ;
    float* Bn   = Mu   + SUMSZ;
    float* mIn  = Bn   + SUMSZ;
    float* nIn  = mIn  + SUMSZ;
    float* Th   = nIn  + SUMSZ;
    float* Dd   = Th   + SUMSZ;
    float* Ee   = Dd   + SUMSZ;
    bf16*  DM   = (bf16*)(Ee + SUMSZ);                // 4*64*65536 bf16 = 32 MiB
    bf16*  WhT  = DM + (size_t)BATCH*NCH*MSLOT;
    bf16*  WlT  = WhT + 1536*256;
    bf16*  xh   = WlT + 1536*256;
    bf16*  xl   = xh + PLANE;

    pack_w<<<dim3(96), dim3(256), 0, stream>>>(Wq, Wk, Wv, Wg, WhT, WlT);
    split_x<<<dim3(1024), dim3(256), 0, stream>>>(x, xh, xl);
    proj_gemm<<<dim3(64, 12), dim3(256), 0, stream>>>(xh, xl, WhT, WlT, bq, bk, bv, bg, input_bias,
                                                      qP, kP, vP, liP, lfP, soP);
    s2_dm<<<dim3(BATCH*NCH), dim3(256), 0, stream>>>(kP, vP, liP, lfP, Csum, Mu, Bn, DM);
    chunk_compose<<<dim3(BATCH), dim3(256), 0, stream>>>(Csum, Mu, Bn, mIn, nIn, Th, Dd, Ee);
    s3_compose<<<dim3(BATCH*256), dim3(256), 0, stream>>>(Dd, Ee, DM);
    s4_chunk<<<dim3(BATCH*NCH), dim3(256), 0, stream>>>(qP, kP, vP, liP, lfP, soP,
                                                        mIn, nIn, Th, DM, norm_scale, out);
}

// Round 10
// 151.266 us; speedup vs baseline: 1.0353x; 1.0353x over previous
//
#include <hip/hip_runtime.h>
#include <hip/hip_bf16.h>
#include <math.h>

#define T_LEN 2048
#define BATCH 4
#define DMODEL 256
#define MROWS (BATCH*T_LEN)
#define PLANE (MROWS*DMODEL)
#define CH_L 32
#define NCH  (T_LEN/CH_L)          // 64
#define SUMSZ (BATCH*NCH*DMODEL)   // 65536
#define MSLOT (DMODEL*DMODEL)      // 65536

typedef __bf16 bf16;
typedef __bf16 bf16x4 __attribute__((ext_vector_type(4)));
typedef __bf16 bf16x8 __attribute__((ext_vector_type(8)));
typedef float  f32x4  __attribute__((ext_vector_type(4)));
typedef unsigned short u16;
typedef u16 u16x8 __attribute__((ext_vector_type(8)));
typedef unsigned int u32;

#define MFMA(a,b,c) __builtin_amdgcn_mfma_f32_16x16x32_bf16(a, b, c, 0, 0, 0)

__device__ __forceinline__ void split_bf16(float x, bf16& hi, bf16& lo) {
    hi = (bf16)x;
    lo = (bf16)(x - (float)hi);
}

// fast transcendentals (hardware v_exp_f32 based)
__device__ __forceinline__ float tanh_fast(float z) {
    z = fminf(fmaxf(z, -15.f), 15.f);
    float e = __expf(2.f * z);
    return (e - 1.f) / (e + 1.f);
}
__device__ __forceinline__ float nsoftplus_fast(float y) {   // -softplus(y)
    return -(fmaxf(y, 0.f) + __logf(1.f + __expf(-fabsf(y))));
}
__device__ __forceinline__ float sigmoid_fast(float y) {
    return 1.f / (1.f + __expf(-y));
}

// ---------------- split x into bf16 hi/lo planes (grid = PLANE/2048 = 1024)
__global__ __launch_bounds__(256) void split_x(const float* __restrict__ x,
                                               bf16* __restrict__ xh,
                                               bf16* __restrict__ xl) {
    int i = (blockIdx.x*256 + threadIdx.x) * 8;
    f32x4 a = *(const f32x4*)(x + i);
    f32x4 b = *(const f32x4*)(x + i + 4);
    bf16x8 h, l;
    #pragma unroll
    for (int e = 0; e < 4; ++e) {
        bf16 hh, ll;
        split_bf16(a[e], hh, ll); h[e] = hh;   l[e] = ll;
        split_bf16(b[e], hh, ll); h[4+e] = hh; l[4+e] = ll;
    }
    *(bf16x8*)(xh + i) = h;
    *(bf16x8*)(xl + i) = l;
}

// ---------------- pack weights (coalesced LDS transpose): WcatT[n][k] hi/lo, n in [0,1536)
__global__ __launch_bounds__(256) void pack_w(const float* __restrict__ Wq,
                                              const float* __restrict__ Wk,
                                              const float* __restrict__ Wv,
                                              const float* __restrict__ Wg,
                                              bf16* __restrict__ WhT,
                                              bf16* __restrict__ WlT) {
    __shared__ float tile[16][260];   // [n-local][k]
    const int tid = threadIdx.x;
    const int n0 = blockIdx.x * 16;
    const float* src; int nb, nw;
    if (n0 < 256)      { src = Wq; nb = n0;       nw = 256; }
    else if (n0 < 512) { src = Wk; nb = n0 - 256; nw = 256; }
    else if (n0 < 768) { src = Wv; nb = n0 - 512; nw = 256; }
    else               { src = Wg; nb = n0 - 768; nw = 768; }
    const int j = tid & 15, kk = tid >> 4;
    #pragma unroll
    for (int r = 0; r < 16; ++r) {
        int k = r*16 + kk;
        tile[j][k] = src[(size_t)k*nw + nb + j];
    }
    __syncthreads();
    #pragma unroll
    for (int r = 0; r < 16; ++r) {
        float v = tile[r][tid];
        bf16 h, l; split_bf16(v, h, l);
        WhT[(size_t)(n0 + r)*256 + tid] = h;
        WlT[(size_t)(n0 + r)*256 + tid] = l;
    }
}

// ---------------- fused projection GEMM (R8 form): no LDS/barriers; register
// double-buffer, compiler-scheduled. [8192,256] x [256,1536].
__global__ __launch_bounds__(256, 2) void proj_gemm(
    const bf16* __restrict__ xh, const bf16* __restrict__ xl,
    const bf16* __restrict__ WhT, const bf16* __restrict__ WlT,
    const float* __restrict__ bq, const float* __restrict__ bk, const float* __restrict__ bv,
    const float* __restrict__ bg, const float* __restrict__ input_bias,
    float* __restrict__ qP, float* __restrict__ kP, float* __restrict__ vP,
    float* __restrict__ liP, float* __restrict__ lfP, float* __restrict__ soP)
{
    const int tid = threadIdx.x;
    const int w = tid >> 6, l = tid & 63;
    const int wr = w >> 1, wc = w & 1;
    const int m0 = blockIdx.x * 128;
    const int n0 = blockIdx.y * 128;
    const int lr = l & 15, lk = l >> 4;

    const bf16 *ahp[4], *alp[4], *bhp[4], *blp[4];
    #pragma unroll
    for (int mi = 0; mi < 4; ++mi) {
        size_t ro = (size_t)(m0 + wr*64 + mi*16 + lr)*256 + lk*8;
        ahp[mi] = xh + ro; alp[mi] = xl + ro;
    }
    #pragma unroll
    for (int ni = 0; ni < 4; ++ni) {
        size_t co = (size_t)(n0 + wc*64 + ni*16 + lr)*256 + lk*8;
        bhp[ni] = WhT + co; blp[ni] = WlT + co;
    }

    f32x4 acc[4][4] = {};
    bf16x8 a0h[4], a0l[4], b0h[4], b0l[4];
    bf16x8 a1h[4], a1l[4], b1h[4], b1l[4];

    #define LOADF(AH, AL, BH, BL, OFF) { \
        _Pragma("unroll") \
        for (int mi = 0; mi < 4; ++mi) { \
            AH[mi] = *(const bf16x8*)(ahp[mi] + (OFF)); \
            AL[mi] = *(const bf16x8*)(alp[mi] + (OFF)); } \
        _Pragma("unroll") \
        for (int ni = 0; ni < 4; ++ni) { \
            BH[ni] = *(const bf16x8*)(bhp[ni] + (OFF)); \
            BL[ni] = *(const bf16x8*)(blp[ni] + (OFF)); } }

    #define MFMAS(AH, AL, BH, BL) { \
        _Pragma("unroll") \
        for (int ni = 0; ni < 4; ++ni) \
            _Pragma("unroll") \
            for (int mi = 0; mi < 4; ++mi) { \
                acc[mi][ni] = MFMA(AH[mi], BH[ni], acc[mi][ni]); \
                acc[mi][ni] = MFMA(AL[mi], BH[ni], acc[mi][ni]); \
                acc[mi][ni] = MFMA(AH[mi], BL[ni], acc[mi][ni]); } }

    LOADF(a0h, a0l, b0h, b0l, 0)
    #pragma unroll
    for (int kk = 0; kk < 4; ++kk) {
        LOADF(a1h, a1l, b1h, b1l, kk*64 + 32)
        MFMAS(a0h, a0l, b0h, b0l)
        if (kk < 3) LOADF(a0h, a0l, b0h, b0l, kk*64 + 64)
        MFMAS(a1h, a1l, b1h, b1l)
    }
    #undef LOADF
    #undef MFMAS

    const int seg = n0 >> 8;   // 0=q 1=k 2=v 3=i 4=f 5=o (uniform per wg)
    #pragma unroll
    for (int mi = 0; mi < 4; ++mi) {
        #pragma unroll
        for (int ni = 0; ni < 4; ++ni) {
            int gcol = n0 + wc*64 + ni*16 + lr;
            int c = gcol & 255;
            #pragma unroll
            for (int r = 0; r < 4; ++r) {
                int grow = m0 + wr*64 + mi*16 + lk*4 + r;
                float val = acc[mi][ni][r];
                size_t o = (size_t)grow*256 + c;
                if (seg == 0)      qP[o] = val + bq[c];
                else if (seg == 1) kP[o] = (val + bk[c]) * 0.0625f;
                else if (seg == 2) vP[o] = val + bv[c];
                else if (seg == 3) { float y = val + bg[c] + input_bias[c];
                                     liP[o] = 10.0f * tanh_fast(y * 0.1f); }
                else if (seg == 4) { float y = val + bg[256 + c];
                                     lfP[o] = nsoftplus_fast(y); }
                else               { float y = val + bg[512 + c];
                                     soP[o] = sigmoid_fast(y); }
            }
        }
    }
}

// ---------------- fused chunk summary + Delta-M: per (b,c): C/mu/Bn (per dim) and
// DM[b,c] = Bhat_mu^T K (256x256, MFMA) -> bf16, with Bhat in LOCAL mu-scale.
__global__ __launch_bounds__(256) void s2_dm(
    const float* __restrict__ kP, const float* __restrict__ vP,
    const float* __restrict__ liP, const float* __restrict__ lfP,
    float* __restrict__ Csum, float* __restrict__ Mu, float* __restrict__ Bn,
    bf16* __restrict__ DM)
{
    __shared__ bf16 BTh[DMODEL][40], BTl[DMODEL][40];
    __shared__ bf16 KTh[DMODEL][40], KTl[DMODEL][40];
    const int tid = threadIdx.x;
    const int w = tid >> 6, l = tid & 63;
    const int b = blockIdx.x >> 6, c = blockIdx.x & 63;
    const size_t pb = ((size_t)b*T_LEN + (size_t)c*CH_L)*DMODEL;

    {
        float C = 0.f, mu = -3e38f;
        float val[CH_L];
        #pragma unroll
        for (int s = 0; s < CH_L; ++s) {
            size_t o = pb + (size_t)s*DMODEL + tid;
            C += lfP[o];
            val[s] = liP[o] - C;
            mu = fmaxf(mu, val[s]);
        }
        float bn = 0.f;
        #pragma unroll
        for (int s = 0; s < CH_L; ++s) {
            size_t o = pb + (size_t)s*DMODEL + tid;
            float e = __expf(val[s] - mu);
            float kv = kP[o];
            bn += e * kv;
            float bv = e * vP[o];
            bf16 h, lo; split_bf16(bv, h, lo);
            BTh[tid][s] = h; BTl[tid][s] = lo;
            bf16 kh, kl; split_bf16(kv, kh, kl);
            KTh[tid][s] = kh; KTl[tid][s] = kl;
        }
        size_t so = ((size_t)b*NCH + c)*DMODEL + tid;
        Csum[so] = C; Mu[so] = mu; Bn[so] = bn;
    }
    __syncthreads();

    const int lr = l & 15, lk = l >> 4;
    bf16x8 Ah[4], Al[4];
    #pragma unroll
    for (int it = 0; it < 4; ++it) {
        int row = w*64 + it*16 + lr;
        Ah[it] = *(const bf16x8*)&BTh[row][lk*8];
        Al[it] = *(const bf16x8*)&BTl[row][lk*8];
    }
    bf16* DMc = DM + (size_t)((size_t)b*NCH + c)*MSLOT;
    #pragma unroll
    for (int jt = 0; jt < 16; ++jt) {
        int jcol = jt*16 + lr;
        bf16x8 bh = *(const bf16x8*)&KTh[jcol][lk*8];
        bf16x8 bl = *(const bf16x8*)&KTl[jcol][lk*8];
        #pragma unroll
        for (int it = 0; it < 4; ++it) {
            f32x4 a = {0.f,0.f,0.f,0.f};
            a = MFMA(Ah[it], bh, a);
            a = MFMA(Al[it], bh, a);
            a = MFMA(Ah[it], bl, a);
            #pragma unroll
            for (int r = 0; r < 4; ++r)
                DMc[(size_t)(w*64 + it*16 + lk*4 + r)*DMODEL + jcol] = (bf16)a[r];
        }
    }
}

// ---------------- sequential compose of (m,n) boundary states across 64 chunks (tiny)
__global__ __launch_bounds__(256) void chunk_compose(
    const float* __restrict__ Csum, const float* __restrict__ Mu, const float* __restrict__ Bn,
    float* __restrict__ mIn, float* __restrict__ nIn, float* __restrict__ Th,
    float* __restrict__ Dd, float* __restrict__ Ee)
{
    const int b = blockIdx.x;
    const int j = threadIdx.x;
    float m = 0.f, n = 0.f;
    for (int c = 0; c < NCH; ++c) {
        size_t o = ((size_t)b*NCH + c)*DMODEL + j;
        mIn[o] = m; nIn[o] = n;
        float cs = Csum[o], mu = Mu[o], bn = Bn[o];
        float th = fmaxf(m, mu);
        Th[o] = th;
        float emu = __expf(mu - th);
        Dd[o] = __expf(m - th);
        Ee[o] = emu;
        n = __expf(m - th)*n + emu*bn;
        m = cs + th;
    }
}

// ---------------- compose M across chunks per (b,i,j); bf16 in/out, fp32 accumulate.
// 4-deep load batching to overlap the 128KB-strided HBM latencies.
__global__ __launch_bounds__(256) void s3_compose(
    const float* __restrict__ Dd, const float* __restrict__ Ee, bf16* __restrict__ DM)
{
    const int b = blockIdx.x >> 8, i = blockIdx.x & 255;
    const int j = threadIdx.x;
    float acc = 0.f;
    const size_t base = ((size_t)b*NCH)*MSLOT + (size_t)i*DMODEL + j;
    const size_t sb = (size_t)b*NCH*DMODEL + i;
    #pragma unroll 1
    for (int c = 0; c < NCH; c += 4) {
        float dm0 = (float)DM[base + (size_t)(c+0)*MSLOT];
        float dm1 = (float)DM[base + (size_t)(c+1)*MSLOT];
        float dm2 = (float)DM[base + (size_t)(c+2)*MSLOT];
        float dm3 = (float)DM[base + (size_t)(c+3)*MSLOT];
        float d0 = Dd[sb + (size_t)(c+0)*DMODEL], e0 = Ee[sb + (size_t)(c+0)*DMODEL];
        float d1 = Dd[sb + (size_t)(c+1)*DMODEL], e1 = Ee[sb + (size_t)(c+1)*DMODEL];
        float d2 = Dd[sb + (size_t)(c+2)*DMODEL], e2 = Ee[sb + (size_t)(c+2)*DMODEL];
        float d3 = Dd[sb + (size_t)(c+3)*DMODEL], e3 = Ee[sb + (size_t)(c+3)*DMODEL];
        if (c > 0) DM[base + (size_t)(c+0)*MSLOT] = (bf16)acc;
        acc = d0*acc + e0*dm0;
        DM[base + (size_t)(c+1)*MSLOT] = (bf16)acc;
        acc = d1*acc + e1*dm1;
        DM[base + (size_t)(c+2)*MSLOT] = (bf16)acc;
        acc = d2*acc + e2*dm2;
        DM[base + (size_t)(c+3)*MSLOT] = (bf16)acc;
        acc = d3*acc + e3*dm3;
    }
}

// ---------------- per-chunk output + fused RMSNorm (rebuilt, 74KB LDS -> 2 wg/CU):
// h = F1*(inter + ex*intra); out = sigma(o)*h/denom / rms * scale.
// Single-pass bf16 for G, Q*M (M is bf16 anyway). GT fully written (bug fix).
__global__ __launch_bounds__(256) void s4_chunk(
    const float* __restrict__ qP, const float* __restrict__ kP, const float* __restrict__ vP,
    const float* __restrict__ liP, const float* __restrict__ lfP, const float* __restrict__ soP,
    const float* __restrict__ mIn, const float* __restrict__ nIn, const float* __restrict__ Th,
    const bf16* __restrict__ DM, const float* __restrict__ norm_scale,
    float* __restrict__ out)
{
    __shared__ __align__(16) char kqbuf[33792];         // Kf/Qf bf16 [32][264] x2; Hout f32 [32][264]
    bf16 (*Kf)[264] = (bf16(*)[264])kqbuf;
    bf16 (*Qf)[264] = (bf16(*)[264])(kqbuf + 16896);
    float (*Hout)[264] = (float(*)[264])kqbuf;
    __shared__ bf16 F1L[CH_L][264];
    __shared__ __align__(16) bf16 BTh[DMODEL][40];
    __shared__ __align__(16) bf16 GT[CH_L][48];
    __shared__ float part[CH_L][4];
    __shared__ float denoms[CH_L];
    __shared__ float exL[DMODEL];

    const int tid = threadIdx.x;
    const int w = tid >> 6, l = tid & 63;
    const int b = blockIdx.x >> 6;
    const int c = blockIdx.x & 63;
    const size_t pb = ((size_t)b*T_LEN + (size_t)c*CH_L)*DMODEL;

    // phase 1: per-dim recurrences (thread = dim); fills Kf/Qf/F1L/BTh + P regs
    const int i = tid;
    const size_t cbx = ((size_t)b*NCH + c)*DMODEL + i;
    const float thL = Th[cbx];
    const float mI = mIn[cbx];
    float P[CH_L];
    {
        float C = 0.f, mu = -3e38f, n = nIn[cbx], thp = mI;
        #pragma unroll
        for (int t = 0; t < CH_L; ++t) {
            size_t o = pb + (size_t)t*DMODEL + i;
            float lf = lfP[o], li = liP[o], kv = kP[o], qv = qP[o], vv = vP[o];
            C += lf;
            float vlc = li - C;
            mu = fmaxf(mu, vlc);
            float tht = fmaxf(mI, mu);
            float f = __expf(thp - tht);
            float iv = __expf(vlc - tht);
            n = f*n + iv*kv;
            thp = tht;
            P[t] = n * qv;
            Kf[t][i] = (bf16)kv;
            Qf[t][i] = (bf16)qv;
            F1L[t][i] = (bf16)__expf(mI - tht);
            BTh[i][t] = (bf16)(__expf(vlc - thL) * vv);
        }
        exL[i] = __expf(thL - mI);
    }
    // phase 2: wave-reduce P over 64 lanes -> part[t][w]
    #pragma unroll
    for (int t = 0; t < CH_L; ++t) {
        float s = P[t];
        #pragma unroll
        for (int sh = 32; sh; sh >>= 1) s += __shfl_xor(s, sh);
        if (l == 0) part[t][w] = s;
    }
    __syncthreads();

    // phase 3a: denominators (threads 0..31)
    if (tid < CH_L)
        denoms[tid] = fmaxf(fabsf(part[tid][0] + part[tid][1] + part[tid][2] + part[tid][3]), 1e-6f);

    // phase 3b: G = K Q^T single-pass bf16; wave w -> tile (s-half = w&1, t-half = w>>1).
    {
        const int a = w & 1, bb = w >> 1;
        const int lr = l & 15, lk2 = l >> 4;
        if (a == 1 && bb == 0) {
            // fully-masked tile (s>t everywhere): zero-fill (bug fix — was never written)
            bf16x4 z = {(bf16)0.f, (bf16)0.f, (bf16)0.f, (bf16)0.f};
            *(bf16x4*)&GT[lr][16 + lk2*4] = z;
        } else {
            f32x4 g = {0.f,0.f,0.f,0.f};
            #pragma unroll
            for (int ks = 0; ks < 8; ++ks) {
                bf16x8 ah = *(const bf16x8*)&Kf[16*a  + lr][ks*32 + lk2*8];
                bf16x8 bh = *(const bf16x8*)&Qf[16*bb + lr][ks*32 + lk2*8];
                g = MFMA(ah, bh, g);
            }
            bf16x4 gv;
            #pragma unroll
            for (int r = 0; r < 4; ++r) {
                int s = 16*a + lk2*4 + r, t = 16*bb + lr;
                gv[r] = (s <= t) ? (bf16)g[r] : (bf16)0.f;
            }
            *(bf16x4*)&GT[16*bb + lr][16*a + lk2*4] = gv;
        }
    }
    __syncthreads();

    // phase 4: output GEMMs. wave -> (t-half = w&1, i-range = (w>>1)*128)
    const int tt = w & 1;
    const int lr = l & 15, lk2 = l >> 4;
    const int trow = tt*16 + lr;
    f32x4 acc_a[8], acc_b[8];

    {   // intra: G^T x Bhat (K-dim = 32)
        bf16x8 gh = *(const bf16x8*)&GT[trow][lk2*8];
        #pragma unroll
        for (int it = 0; it < 8; ++it) {
            int irow = ((w>>1)*8 + it)*16 + lr;
            bf16x8 bb2 = *(const bf16x8*)&BTh[irow][lk2*8];
            f32x4 a = {0.f,0.f,0.f,0.f};
            acc_a[it] = MFMA(gh, bb2, a);
        }
    }
    #pragma unroll
    for (int it = 0; it < 8; ++it) acc_b[it] = (f32x4){0.f,0.f,0.f,0.f};
    if (c > 0) {   // inter: Q x Mprev^T, single-pass bf16
        const u16* Mbase = (const u16*)DM + (size_t)((size_t)b*NCH + c)*MSLOT;
        #pragma unroll
        for (int ks = 0; ks < 8; ++ks) {
            bf16x8 qh = *(const bf16x8*)&Qf[trow][ks*32 + lk2*8];
            #pragma unroll
            for (int it = 0; it < 8; ++it) {
                int irow = ((w>>1)*8 + it)*16 + lr;
                union { u16x8 u; bf16x8 h; } M8;
                M8.u = *(const u16x8*)(Mbase + (size_t)irow*DMODEL + ks*32 + lk2*8);
                acc_b[it] = MFMA(qh, M8.h, acc_b[it]);
            }
        }
    }
    __syncthreads();   // all Kf/Qf reads done; kqbuf becomes Hout

    // epilogue part 1: combine, divide by denom, park pre-norm h in LDS
    #pragma unroll
    for (int it = 0; it < 8; ++it) {
        int icol = ((w>>1)*8 + it)*16 + lr;
        float ex = exL[icol];
        #pragma unroll
        for (int r = 0; r < 4; ++r) {
            int t = tt*16 + lk2*4 + r;
            float F1 = (float)F1L[t][icol];
            float h = F1 * (acc_b[it][r] + ex * acc_a[it][r]);
            size_t o = pb + (size_t)t*DMODEL + icol;
            Hout[t][icol] = soP[o] * h / denoms[t];
        }
    }
    __syncthreads();
    // epilogue part 2: fused RMSNorm (wave w owns rows w*8..w*8+7), coalesced stores
    #pragma unroll
    for (int r = 0; r < 8; ++r) {
        int t = w*8 + r;
        f32x4 hv = *(const f32x4*)&Hout[t][l*4];
        float ss = hv[0]*hv[0] + hv[1]*hv[1] + hv[2]*hv[2] + hv[3]*hv[3];
        #pragma unroll
        for (int sh = 32; sh; sh >>= 1) ss += __shfl_xor(ss, sh);
        float rinv = rsqrtf(ss * (1.0f/256.0f) + 1e-8f);
        f32x4 ns = *(const f32x4*)(norm_scale + l*4);
        f32x4 o4;
        #pragma unroll
        for (int e = 0; e < 4; ++e) o4[e] = hv[e] * rinv * ns[e];
        *(f32x4*)(out + pb + (size_t)t*DMODEL + l*4) = o4;
    }
}

extern "C" void kernel_launch(void* const* d_in, const int* in_sizes, int n_in,
                              void* d_out, int out_size, void* d_ws, size_t ws_size,
                              hipStream_t stream) {
    const float* x          = (const float*)d_in[0];
    const float* Wq         = (const float*)d_in[1];
    const float* bq         = (const float*)d_in[2];
    const float* Wk         = (const float*)d_in[3];
    const float* bk         = (const float*)d_in[4];
    const float* Wv         = (const float*)d_in[5];
    const float* bv         = (const float*)d_in[6];
    const float* Wg         = (const float*)d_in[7];
    const float* bg         = (const float*)d_in[8];
    const float* input_bias = (const float*)d_in[9];
    const float* norm_scale = (const float*)d_in[10];
    float* out = (float*)d_out;

    float* qP   = (float*)d_ws;
    float* kP   = qP  + PLANE;
    float* vP   = kP  + PLANE;
    float* liP  = vP  + PLANE;
    float* lfP  = liP + PLANE;
    float* soP  = lfP + PLANE;
    float* Csum = soP + PLANE;
    float* Mu   = Csum + SUMSZ;
    float* Bn   = Mu   + SUMSZ;
    float* mIn  = Bn   + SUMSZ;
    float* nIn  = mIn  + SUMSZ;
    float* Th   = nIn  + SUMSZ;
    float* Dd   = Th   + SUMSZ;
    float* Ee   = Dd   + SUMSZ;
    bf16*  DM   = (bf16*)(Ee + SUMSZ);                // 4*64*65536 bf16 = 32 MiB
    bf16*  WhT  = DM + (size_t)BATCH*NCH*MSLOT;
    bf16*  WlT  = WhT + 1536*256;
    bf16*  xh   = WlT + 1536*256;
    bf16*  xl   = xh + PLANE;

    pack_w<<<dim3(96), dim3(256), 0, stream>>>(Wq, Wk, Wv, Wg, WhT, WlT);
    split_x<<<dim3(1024), dim3(256), 0, stream>>>(x, xh, xl);
    proj_gemm<<<dim3(64, 12), dim3(256), 0, stream>>>(xh, xl, WhT, WlT, bq, bk, bv, bg, input_bias,
                                                      qP, kP, vP, liP, lfP, soP);
    s2_dm<<<dim3(BATCH*NCH), dim3(256), 0, stream>>>(kP, vP, liP, lfP, Csum, Mu, Bn, DM);
    chunk_compose<<<dim3(BATCH), dim3(256), 0, stream>>>(Csum, Mu, Bn, mIn, nIn, Th, Dd, Ee);
    s3_compose<<<dim3(BATCH*256), dim3(256), 0, stream>>>(Dd, Ee, DM);
    s4_chunk<<<dim3(BATCH*NCH), dim3(256), 0, stream>>>(qP, kP, vP, liP, lfP, soP,
                                                        mIn, nIn, Th, DM, norm_scale, out);
}

// Round 11
// 139.640 us; speedup vs baseline: 1.1215x; 1.0833x over previous
//
#include <hip/hip_runtime.h>
#include <hip/hip_bf16.h>
#include <math.h>

#define T_LEN 2048
#define BATCH 4
#define DMODEL 256
#define MROWS (BATCH*T_LEN)
#define PLANE (MROWS*DMODEL)
#define CH_L 32
#define NCH  (T_LEN/CH_L)          // 64
#define SUMSZ (BATCH*NCH*DMODEL)   // 65536
#define MSLOT (DMODEL*DMODEL)      // 65536

typedef __bf16 bf16;
typedef __bf16 bf16x4 __attribute__((ext_vector_type(4)));
typedef __bf16 bf16x8 __attribute__((ext_vector_type(8)));
typedef float  f32x4  __attribute__((ext_vector_type(4)));
typedef unsigned short u16;
typedef u16 u16x8 __attribute__((ext_vector_type(8)));
typedef unsigned int u32;

#define MFMA(a,b,c) __builtin_amdgcn_mfma_f32_16x16x32_bf16(a, b, c, 0, 0, 0)

__device__ __forceinline__ void split_bf16(float x, bf16& hi, bf16& lo) {
    hi = (bf16)x;
    lo = (bf16)(x - (float)hi);
}

// fast transcendentals (hardware v_exp_f32 based)
__device__ __forceinline__ float tanh_fast(float z) {
    z = fminf(fmaxf(z, -15.f), 15.f);
    float e = __expf(2.f * z);
    return (e - 1.f) / (e + 1.f);
}
__device__ __forceinline__ float nsoftplus_fast(float y) {   // -softplus(y)
    return -(fmaxf(y, 0.f) + __logf(1.f + __expf(-fabsf(y))));
}
__device__ __forceinline__ float sigmoid_fast(float y) {
    return 1.f / (1.f + __expf(-y));
}

#define GLD16(SRC, DST) __builtin_amdgcn_global_load_lds( \
    (const __attribute__((address_space(1))) void*)(SRC), \
    (__attribute__((address_space(3))) void*)(DST), 16, 0, 0)

// ---------------- split x into bf16 hi/lo planes (grid = PLANE/2048 = 1024)
__global__ __launch_bounds__(256) void split_x(const float* __restrict__ x,
                                               bf16* __restrict__ xh,
                                               bf16* __restrict__ xl) {
    int i = (blockIdx.x*256 + threadIdx.x) * 8;
    f32x4 a = *(const f32x4*)(x + i);
    f32x4 b = *(const f32x4*)(x + i + 4);
    bf16x8 h, l;
    #pragma unroll
    for (int e = 0; e < 4; ++e) {
        bf16 hh, ll;
        split_bf16(a[e], hh, ll); h[e] = hh;   l[e] = ll;
        split_bf16(b[e], hh, ll); h[4+e] = hh; l[4+e] = ll;
    }
    *(bf16x8*)(xh + i) = h;
    *(bf16x8*)(xl + i) = l;
}

// ---------------- pack weights (coalesced LDS transpose): WcatT[n][k] hi/lo, n in [0,1536)
__global__ __launch_bounds__(256) void pack_w(const float* __restrict__ Wq,
                                              const float* __restrict__ Wk,
                                              const float* __restrict__ Wv,
                                              const float* __restrict__ Wg,
                                              bf16* __restrict__ WhT,
                                              bf16* __restrict__ WlT) {
    __shared__ float tile[16][260];   // [n-local][k]
    const int tid = threadIdx.x;
    const int n0 = blockIdx.x * 16;
    const float* src; int nb, nw;
    if (n0 < 256)      { src = Wq; nb = n0;       nw = 256; }
    else if (n0 < 512) { src = Wk; nb = n0 - 256; nw = 256; }
    else if (n0 < 768) { src = Wv; nb = n0 - 512; nw = 256; }
    else               { src = Wg; nb = n0 - 768; nw = 768; }
    const int j = tid & 15, kk = tid >> 4;
    #pragma unroll
    for (int r = 0; r < 16; ++r) {
        int k = r*16 + kk;
        tile[j][k] = src[(size_t)k*nw + nb + j];
    }
    __syncthreads();
    #pragma unroll
    for (int r = 0; r < 16; ++r) {
        float v = tile[r][tid];
        bf16 h, l; split_bf16(v, h, l);
        WhT[(size_t)(n0 + r)*256 + tid] = h;
        WlT[(size_t)(n0 + r)*256 + tid] = l;
    }
}

// ---------------- fused projection GEMM (m97 structure + T2 swizzle):
// 128x128 tile, BK=32, single-buffered 32KB LDS (4 bf16 planes), global_load_lds 16B
// with pre-swizzled source columns; swizzled b128 fragment reads (2-way, free).
// 3 blocks/CU resident -> barrier drain hidden by cross-block MFMA overlap.
__global__ __launch_bounds__(256) void proj_gemm(
    const bf16* __restrict__ xh, const bf16* __restrict__ xl,
    const bf16* __restrict__ WhT, const bf16* __restrict__ WlT,
    const float* __restrict__ bq, const float* __restrict__ bk, const float* __restrict__ bv,
    const float* __restrict__ bg, const float* __restrict__ input_bias,
    float* __restrict__ qP, float* __restrict__ kP, float* __restrict__ vP,
    float* __restrict__ liP, float* __restrict__ lfP, float* __restrict__ soP)
{
    __shared__ bf16 Ah[128*32];
    __shared__ bf16 Al[128*32];
    __shared__ bf16 Bh[128*32];
    __shared__ bf16 Bl[128*32];
    const int tid = threadIdx.x;
    const int w = tid >> 6, l = tid & 63;
    const int wr = w >> 1, wc = w & 1;
    const int m0 = blockIdx.x * 128;
    const int n0 = blockIdx.y * 128;
    const int lr = l & 15, lk = l >> 4;

    f32x4 acc[4][4] = {};

    for (int kt = 0; kt < 256; kt += 32) {
        // stage: LDS linear dest, source column pre-swizzled (rule #21)
        #pragma unroll
        for (int p = 0; p < 2; ++p) {
            int e = p*2048 + tid*8;            // flat bf16 element in [128][32] tile
            int row = e >> 5;
            int cb  = (e >> 3) & 3;            // 16B slot within row
            int scol = ((cb ^ ((row >> 1) & 3)) << 3);
            size_t ga = (size_t)(m0 + row)*256 + kt + scol;
            size_t gb = (size_t)(n0 + row)*256 + kt + scol;
            GLD16(xh + ga, Ah + e);
            GLD16(xl + ga, Al + e);
            GLD16(WhT + gb, Bh + e);
            GLD16(WlT + gb, Bl + e);
        }
        __syncthreads();

        bf16x8 afh[4], afl[4], bfh[4], bfl[4];
        #pragma unroll
        for (int mi = 0; mi < 4; ++mi) {
            int row = wr*64 + mi*16 + lr;
            int slot = lk ^ ((row >> 1) & 3);
            afh[mi] = *(const bf16x8*)(Ah + row*32 + slot*8);
            afl[mi] = *(const bf16x8*)(Al + row*32 + slot*8);
        }
        #pragma unroll
        for (int ni = 0; ni < 4; ++ni) {
            int row = wc*64 + ni*16 + lr;
            int slot = lk ^ ((row >> 1) & 3);
            bfh[ni] = *(const bf16x8*)(Bh + row*32 + slot*8);
            bfl[ni] = *(const bf16x8*)(Bl + row*32 + slot*8);
        }
        #pragma unroll
        for (int ni = 0; ni < 4; ++ni)
            #pragma unroll
            for (int mi = 0; mi < 4; ++mi) {
                acc[mi][ni] = MFMA(afh[mi], bfh[ni], acc[mi][ni]);
                acc[mi][ni] = MFMA(afl[mi], bfh[ni], acc[mi][ni]);
                acc[mi][ni] = MFMA(afh[mi], bfl[ni], acc[mi][ni]);
            }
        __syncthreads();
    }

    const int seg = n0 >> 8;   // 0=q 1=k 2=v 3=i 4=f 5=o (uniform per wg)
    #pragma unroll
    for (int mi = 0; mi < 4; ++mi) {
        #pragma unroll
        for (int ni = 0; ni < 4; ++ni) {
            int gcol = n0 + wc*64 + ni*16 + lr;
            int c = gcol & 255;
            #pragma unroll
            for (int r = 0; r < 4; ++r) {
                int grow = m0 + wr*64 + mi*16 + lk*4 + r;
                float val = acc[mi][ni][r];
                size_t o = (size_t)grow*256 + c;
                if (seg == 0)      qP[o] = val + bq[c];
                else if (seg == 1) kP[o] = (val + bk[c]) * 0.0625f;
                else if (seg == 2) vP[o] = val + bv[c];
                else if (seg == 3) { float y = val + bg[c] + input_bias[c];
                                     liP[o] = 10.0f * tanh_fast(y * 0.1f); }
                else if (seg == 4) { float y = val + bg[256 + c];
                                     lfP[o] = nsoftplus_fast(y); }
                else               { float y = val + bg[512 + c];
                                     soP[o] = sigmoid_fast(y); }
            }
        }
    }
}

// ---------------- fused chunk summary + Delta-M: per (b,c): C/mu/Bn (per dim) and
// DM[b,c] = Bhat_mu^T K (256x256, MFMA) -> bf16, with Bhat in LOCAL mu-scale.
__global__ __launch_bounds__(256) void s2_dm(
    const float* __restrict__ kP, const float* __restrict__ vP,
    const float* __restrict__ liP, const float* __restrict__ lfP,
    float* __restrict__ Csum, float* __restrict__ Mu, float* __restrict__ Bn,
    bf16* __restrict__ DM)
{
    __shared__ bf16 BTh[DMODEL][40], BTl[DMODEL][40];
    __shared__ bf16 KTh[DMODEL][40], KTl[DMODEL][40];
    const int tid = threadIdx.x;
    const int w = tid >> 6, l = tid & 63;
    const int b = blockIdx.x >> 6, c = blockIdx.x & 63;
    const size_t pb = ((size_t)b*T_LEN + (size_t)c*CH_L)*DMODEL;

    {
        float C = 0.f, mu = -3e38f;
        float val[CH_L];
        #pragma unroll
        for (int s = 0; s < CH_L; ++s) {
            size_t o = pb + (size_t)s*DMODEL + tid;
            C += lfP[o];
            val[s] = liP[o] - C;
            mu = fmaxf(mu, val[s]);
        }
        float bn = 0.f;
        #pragma unroll
        for (int s = 0; s < CH_L; ++s) {
            size_t o = pb + (size_t)s*DMODEL + tid;
            float e = __expf(val[s] - mu);
            float kv = kP[o];
            bn += e * kv;
            float bv = e * vP[o];
            bf16 h, lo; split_bf16(bv, h, lo);
            BTh[tid][s] = h; BTl[tid][s] = lo;
            bf16 kh, kl; split_bf16(kv, kh, kl);
            KTh[tid][s] = kh; KTl[tid][s] = kl;
        }
        size_t so = ((size_t)b*NCH + c)*DMODEL + tid;
        Csum[so] = C; Mu[so] = mu; Bn[so] = bn;
    }
    __syncthreads();

    const int lr = l & 15, lk = l >> 4;
    bf16x8 Ah[4], Al[4];
    #pragma unroll
    for (int it = 0; it < 4; ++it) {
        int row = w*64 + it*16 + lr;
        Ah[it] = *(const bf16x8*)&BTh[row][lk*8];
        Al[it] = *(const bf16x8*)&BTl[row][lk*8];
    }
    bf16* DMc = DM + (size_t)((size_t)b*NCH + c)*MSLOT;
    #pragma unroll
    for (int jt = 0; jt < 16; ++jt) {
        int jcol = jt*16 + lr;
        bf16x8 bh = *(const bf16x8*)&KTh[jcol][lk*8];
        bf16x8 bl = *(const bf16x8*)&KTl[jcol][lk*8];
        #pragma unroll
        for (int it = 0; it < 4; ++it) {
            f32x4 a = {0.f,0.f,0.f,0.f};
            a = MFMA(Ah[it], bh, a);
            a = MFMA(Al[it], bh, a);
            a = MFMA(Ah[it], bl, a);
            #pragma unroll
            for (int r = 0; r < 4; ++r)
                DMc[(size_t)(w*64 + it*16 + lk*4 + r)*DMODEL + jcol] = (bf16)a[r];
        }
    }
}

// ---------------- sequential compose of (m,n) boundary states across 64 chunks (tiny)
__global__ __launch_bounds__(256) void chunk_compose(
    const float* __restrict__ Csum, const float* __restrict__ Mu, const float* __restrict__ Bn,
    float* __restrict__ mIn, float* __restrict__ nIn, float* __restrict__ Th,
    float* __restrict__ Dd, float* __restrict__ Ee)
{
    const int b = blockIdx.x;
    const int j = threadIdx.x;
    float m = 0.f, n = 0.f;
    for (int c = 0; c < NCH; ++c) {
        size_t o = ((size_t)b*NCH + c)*DMODEL + j;
        mIn[o] = m; nIn[o] = n;
        float cs = Csum[o], mu = Mu[o], bn = Bn[o];
        float th = fmaxf(m, mu);
        Th[o] = th;
        float emu = __expf(mu - th);
        Dd[o] = __expf(m - th);
        Ee[o] = emu;
        n = __expf(m - th)*n + emu*bn;
        m = cs + th;
    }
}

// ---------------- compose M across chunks per (b,i,j); bf16 in/out, fp32 accumulate.
// 4-deep load batching to overlap the 128KB-strided HBM latencies.
__global__ __launch_bounds__(256) void s3_compose(
    const float* __restrict__ Dd, const float* __restrict__ Ee, bf16* __restrict__ DM)
{
    const int b = blockIdx.x >> 8, i = blockIdx.x & 255;
    const int j = threadIdx.x;
    float acc = 0.f;
    const size_t base = ((size_t)b*NCH)*MSLOT + (size_t)i*DMODEL + j;
    const size_t sb = (size_t)b*NCH*DMODEL + i;
    #pragma unroll 1
    for (int c = 0; c < NCH; c += 4) {
        float dm0 = (float)DM[base + (size_t)(c+0)*MSLOT];
        float dm1 = (float)DM[base + (size_t)(c+1)*MSLOT];
        float dm2 = (float)DM[base + (size_t)(c+2)*MSLOT];
        float dm3 = (float)DM[base + (size_t)(c+3)*MSLOT];
        float d0 = Dd[sb + (size_t)(c+0)*DMODEL], e0 = Ee[sb + (size_t)(c+0)*DMODEL];
        float d1 = Dd[sb + (size_t)(c+1)*DMODEL], e1 = Ee[sb + (size_t)(c+1)*DMODEL];
        float d2 = Dd[sb + (size_t)(c+2)*DMODEL], e2 = Ee[sb + (size_t)(c+2)*DMODEL];
        float d3 = Dd[sb + (size_t)(c+3)*DMODEL], e3 = Ee[sb + (size_t)(c+3)*DMODEL];
        if (c > 0) DM[base + (size_t)(c+0)*MSLOT] = (bf16)acc;
        acc = d0*acc + e0*dm0;
        DM[base + (size_t)(c+1)*MSLOT] = (bf16)acc;
        acc = d1*acc + e1*dm1;
        DM[base + (size_t)(c+2)*MSLOT] = (bf16)acc;
        acc = d2*acc + e2*dm2;
        DM[base + (size_t)(c+3)*MSLOT] = (bf16)acc;
        acc = d3*acc + e3*dm3;
    }
}

// ---------------- per-chunk output + fused RMSNorm (74KB LDS -> 2 wg/CU):
// h = F1*(inter + ex*intra); out = sigma(o)*h/denom / rms * scale
__global__ __launch_bounds__(256) void s4_chunk(
    const float* __restrict__ qP, const float* __restrict__ kP, const float* __restrict__ vP,
    const float* __restrict__ liP, const float* __restrict__ lfP, const float* __restrict__ soP,
    const float* __restrict__ mIn, const float* __restrict__ nIn, const float* __restrict__ Th,
    const bf16* __restrict__ DM, const float* __restrict__ norm_scale,
    float* __restrict__ out)
{
    __shared__ __align__(16) char kqbuf[33792];         // Kf/Qf bf16 [32][264] x2; Hout f32 [32][264]
    bf16 (*Kf)[264] = (bf16(*)[264])kqbuf;
    bf16 (*Qf)[264] = (bf16(*)[264])(kqbuf + 16896);
    float (*Hout)[264] = (float(*)[264])kqbuf;
    __shared__ bf16 F1L[CH_L][264];
    __shared__ __align__(16) bf16 BTh[DMODEL][40];
    __shared__ __align__(16) bf16 GT[CH_L][48];
    __shared__ float part[CH_L][4];
    __shared__ float denoms[CH_L];
    __shared__ float exL[DMODEL];

    const int tid = threadIdx.x;
    const int w = tid >> 6, l = tid & 63;
    const int b = blockIdx.x >> 6;
    const int c = blockIdx.x & 63;
    const size_t pb = ((size_t)b*T_LEN + (size_t)c*CH_L)*DMODEL;

    // phase 1: per-dim recurrences (thread = dim); fills Kf/Qf/F1L/BTh + P regs
    const int i = tid;
    const size_t cbx = ((size_t)b*NCH + c)*DMODEL + i;
    const float thL = Th[cbx];
    const float mI = mIn[cbx];
    float P[CH_L];
    {
        float C = 0.f, mu = -3e38f, n = nIn[cbx], thp = mI;
        #pragma unroll
        for (int t = 0; t < CH_L; ++t) {
            size_t o = pb + (size_t)t*DMODEL + i;
            float lf = lfP[o], li = liP[o], kv = kP[o], qv = qP[o], vv = vP[o];
            C += lf;
            float vlc = li - C;
            mu = fmaxf(mu, vlc);
            float tht = fmaxf(mI, mu);
            float f = __expf(thp - tht);
            float iv = __expf(vlc - tht);
            n = f*n + iv*kv;
            thp = tht;
            P[t] = n * qv;
            Kf[t][i] = (bf16)kv;
            Qf[t][i] = (bf16)qv;
            F1L[t][i] = (bf16)__expf(mI - tht);
            BTh[i][t] = (bf16)(__expf(vlc - thL) * vv);
        }
        exL[i] = __expf(thL - mI);
    }
    // phase 2: wave-reduce P over 64 lanes -> part[t][w]
    #pragma unroll
    for (int t = 0; t < CH_L; ++t) {
        float s = P[t];
        #pragma unroll
        for (int sh = 32; sh; sh >>= 1) s += __shfl_xor(s, sh);
        if (l == 0) part[t][w] = s;
    }
    __syncthreads();

    // phase 3a: denominators (threads 0..31)
    if (tid < CH_L)
        denoms[tid] = fmaxf(fabsf(part[tid][0] + part[tid][1] + part[tid][2] + part[tid][3]), 1e-6f);

    // phase 3b: G = K Q^T single-pass bf16; wave w -> tile (s-half = w&1, t-half = w>>1).
    {
        const int a = w & 1, bb = w >> 1;
        const int lr = l & 15, lk2 = l >> 4;
        if (a == 1 && bb == 0) {
            bf16x4 z = {(bf16)0.f, (bf16)0.f, (bf16)0.f, (bf16)0.f};
            *(bf16x4*)&GT[lr][16 + lk2*4] = z;
        } else {
            f32x4 g = {0.f,0.f,0.f,0.f};
            #pragma unroll
            for (int ks = 0; ks < 8; ++ks) {
                bf16x8 ah = *(const bf16x8*)&Kf[16*a  + lr][ks*32 + lk2*8];
                bf16x8 bh = *(const bf16x8*)&Qf[16*bb + lr][ks*32 + lk2*8];
                g = MFMA(ah, bh, g);
            }
            bf16x4 gv;
            #pragma unroll
            for (int r = 0; r < 4; ++r) {
                int s = 16*a + lk2*4 + r, t = 16*bb + lr;
                gv[r] = (s <= t) ? (bf16)g[r] : (bf16)0.f;
            }
            *(bf16x4*)&GT[16*bb + lr][16*a + lk2*4] = gv;
        }
    }
    __syncthreads();

    // phase 4: output GEMMs. wave -> (t-half = w&1, i-range = (w>>1)*128)
    const int tt = w & 1;
    const int lr = l & 15, lk2 = l >> 4;
    const int trow = tt*16 + lr;
    f32x4 acc_a[8], acc_b[8];

    {   // intra: G^T x Bhat (K-dim = 32)
        bf16x8 gh = *(const bf16x8*)&GT[trow][lk2*8];
        #pragma unroll
        for (int it = 0; it < 8; ++it) {
            int irow = ((w>>1)*8 + it)*16 + lr;
            bf16x8 bb2 = *(const bf16x8*)&BTh[irow][lk2*8];
            f32x4 a = {0.f,0.f,0.f,0.f};
            acc_a[it] = MFMA(gh, bb2, a);
        }
    }
    #pragma unroll
    for (int it = 0; it < 8; ++it) acc_b[it] = (f32x4){0.f,0.f,0.f,0.f};
    if (c > 0) {   // inter: Q x Mprev^T, single-pass bf16
        const u16* Mbase = (const u16*)DM + (size_t)((size_t)b*NCH + c)*MSLOT;
        #pragma unroll
        for (int ks = 0; ks < 8; ++ks) {
            bf16x8 qh = *(const bf16x8*)&Qf[trow][ks*32 + lk2*8];
            #pragma unroll
            for (int it = 0; it < 8; ++it) {
                int irow = ((w>>1)*8 + it)*16 + lr;
                union { u16x8 u; bf16x8 h; } M8;
                M8.u = *(const u16x8*)(Mbase + (size_t)irow*DMODEL + ks*32 + lk2*8);
                acc_b[it] = MFMA(qh, M8.h, acc_b[it]);
            }
        }
    }
    __syncthreads();   // all Kf/Qf reads done; kqbuf becomes Hout

    // epilogue part 1: combine, divide by denom, park pre-norm h in LDS
    #pragma unroll
    for (int it = 0; it < 8; ++it) {
        int icol = ((w>>1)*8 + it)*16 + lr;
        float ex = exL[icol];
        #pragma unroll
        for (int r = 0; r < 4; ++r) {
            int t = tt*16 + lk2*4 + r;
            float F1 = (float)F1L[t][icol];
            float h = F1 * (acc_b[it][r] + ex * acc_a[it][r]);
            size_t o = pb + (size_t)t*DMODEL + icol;
            Hout[t][icol] = soP[o] * h / denoms[t];
        }
    }
    __syncthreads();
    // epilogue part 2: fused RMSNorm (wave w owns rows w*8..w*8+7), coalesced stores
    #pragma unroll
    for (int r = 0; r < 8; ++r) {
        int t = w*8 + r;
        f32x4 hv = *(const f32x4*)&Hout[t][l*4];
        float ss = hv[0]*hv[0] + hv[1]*hv[1] + hv[2]*hv[2] + hv[3]*hv[3];
        #pragma unroll
        for (int sh = 32; sh; sh >>= 1) ss += __shfl_xor(ss, sh);
        float rinv = rsqrtf(ss * (1.0f/256.0f) + 1e-8f);
        f32x4 ns = *(const f32x4*)(norm_scale + l*4);
        f32x4 o4;
        #pragma unroll
        for (int e = 0; e < 4; ++e) o4[e] = hv[e] * rinv * ns[e];
        *(f32x4*)(out + pb + (size_t)t*DMODEL + l*4) = o4;
    }
}

extern "C" void kernel_launch(void* const* d_in, const int* in_sizes, int n_in,
                              void* d_out, int out_size, void* d_ws, size_t ws_size,
                              hipStream_t stream) {
    const float* x          = (const float*)d_in[0];
    const float* Wq         = (const float*)d_in[1];
    const float* bq         = (const float*)d_in[2];
    const float* Wk         = (const float*)d_in[3];
    const float* bk         = (const float*)d_in[4];
    const float* Wv         = (const float*)d_in[5];
    const float* bv         = (const float*)d_in[6];
    const float* Wg         = (const float*)d_in[7];
    const float* bg         = (const float*)d_in[8];
    const float* input_bias = (const float*)d_in[9];
    const float* norm_scale = (const float*)d_in[10];
    float* out = (float*)d_out;

    float* qP   = (float*)d_ws;
    float* kP   = qP  + PLANE;
    float* vP   = kP  + PLANE;
    float* liP  = vP  + PLANE;
    float* lfP  = liP + PLANE;
    float* soP  = lfP + PLANE;
    float* Csum = soP + PLANE;
    float* Mu   = Csum + SUMSZ;
    float* Bn   = Mu   + SUMSZ;
    float* mIn  = Bn   + SUMSZ;
    float* nIn  = mIn  + SUMSZ;
    float* Th   = nIn  + SUMSZ;
    float* Dd   = Th   + SUMSZ;
    float* Ee   = Dd   + SUMSZ;
    bf16*  DM   = (bf16*)(Ee + SUMSZ);                // 4*64*65536 bf16 = 32 MiB
    bf16*  WhT  = DM + (size_t)BATCH*NCH*MSLOT;
    bf16*  WlT  = WhT + 1536*256;
    bf16*  xh   = WlT + 1536*256;
    bf16*  xl   = xh + PLANE;

    pack_w<<<dim3(96), dim3(256), 0, stream>>>(Wq, Wk, Wv, Wg, WhT, WlT);
    split_x<<<dim3(1024), dim3(256), 0, stream>>>(x, xh, xl);
    proj_gemm<<<dim3(64, 12), dim3(256), 0, stream>>>(xh, xl, WhT, WlT, bq, bk, bv, bg, input_bias,
                                                      qP, kP, vP, liP, lfP, soP);
    s2_dm<<<dim3(BATCH*NCH), dim3(256), 0, stream>>>(kP, vP, liP, lfP, Csum, Mu, Bn, DM);
    chunk_compose<<<dim3(BATCH), dim3(256), 0, stream>>>(Csum, Mu, Bn, mIn, nIn, Th, Dd, Ee);
    s3_compose<<<dim3(BATCH*256), dim3(256), 0, stream>>>(Dd, Ee, DM);
    s4_chunk<<<dim3(BATCH*NCH), dim3(256), 0, stream>>>(qP, kP, vP, liP, lfP, soP,
                                                        mIn, nIn, Th, DM, norm_scale, out);
}

// Round 12
// 110.242 us; speedup vs baseline: 1.4206x; 1.2667x over previous
//
#include <hip/hip_runtime.h>
#include <hip/hip_bf16.h>
#include <math.h>

#define T_LEN 2048
#define BATCH 4
#define DMODEL 256
#define MROWS (BATCH*T_LEN)
#define PLANE (MROWS*DMODEL)
#define CH_L 32
#define NCH  (T_LEN/CH_L)          // 64
#define SUMSZ (BATCH*NCH*DMODEL)   // 65536
#define MSLOT (DMODEL*DMODEL)      // 65536

typedef __bf16 bf16;
typedef __bf16 bf16x4 __attribute__((ext_vector_type(4)));
typedef __bf16 bf16x8 __attribute__((ext_vector_type(8)));
typedef float  f32x4  __attribute__((ext_vector_type(4)));
typedef unsigned short u16;
typedef u16 u16x8 __attribute__((ext_vector_type(8)));
typedef unsigned int u32;

#define MFMA(a,b,c) __builtin_amdgcn_mfma_f32_16x16x32_bf16(a, b, c, 0, 0, 0)

__device__ __forceinline__ void split_bf16(float x, bf16& hi, bf16& lo) {
    hi = (bf16)x;
    lo = (bf16)(x - (float)hi);
}

// fast transcendentals (hardware v_exp_f32 based)
__device__ __forceinline__ float tanh_fast(float z) {
    z = fminf(fmaxf(z, -15.f), 15.f);
    float e = __expf(2.f * z);
    return (e - 1.f) / (e + 1.f);
}
__device__ __forceinline__ float nsoftplus_fast(float y) {   // -softplus(y)
    return -(fmaxf(y, 0.f) + __logf(1.f + __expf(-fabsf(y))));
}
__device__ __forceinline__ float sigmoid_fast(float y) {
    return 1.f / (1.f + __expf(-y));
}

#define GLD16(SRC, DST) __builtin_amdgcn_global_load_lds( \
    (const __attribute__((address_space(1))) void*)(SRC), \
    (__attribute__((address_space(3))) void*)(DST), 16, 0, 0)

// ---------------- split x into bf16 hi/lo planes (grid = PLANE/2048 = 1024)
__global__ __launch_bounds__(256) void split_x(const float* __restrict__ x,
                                               bf16* __restrict__ xh,
                                               bf16* __restrict__ xl) {
    int i = (blockIdx.x*256 + threadIdx.x) * 8;
    f32x4 a = *(const f32x4*)(x + i);
    f32x4 b = *(const f32x4*)(x + i + 4);
    bf16x8 h, l;
    #pragma unroll
    for (int e = 0; e < 4; ++e) {
        bf16 hh, ll;
        split_bf16(a[e], hh, ll); h[e] = hh;   l[e] = ll;
        split_bf16(b[e], hh, ll); h[4+e] = hh; l[4+e] = ll;
    }
    *(bf16x8*)(xh + i) = h;
    *(bf16x8*)(xl + i) = l;
}

// ---------------- pack weights (coalesced LDS transpose) + fused scale/bias fold:
// Wk scaled by 1/16 (exact pow2); biasC[1536] = {bq, bk/16, bv, bg+ib, bg_f, bg_o}
__global__ __launch_bounds__(256) void pack_w(const float* __restrict__ Wq,
                                              const float* __restrict__ Wk,
                                              const float* __restrict__ Wv,
                                              const float* __restrict__ Wg,
                                              const float* __restrict__ bq,
                                              const float* __restrict__ bk,
                                              const float* __restrict__ bv,
                                              const float* __restrict__ bg,
                                              const float* __restrict__ input_bias,
                                              bf16* __restrict__ WhT,
                                              bf16* __restrict__ WlT,
                                              float* __restrict__ biasC) {
    __shared__ float tile[16][260];   // [n-local][k]
    const int tid = threadIdx.x;
    const int n0 = blockIdx.x * 16;
    const float* src; int nb, nw;
    float scale = 1.0f;
    if (n0 < 256)      { src = Wq; nb = n0;       nw = 256; }
    else if (n0 < 512) { src = Wk; nb = n0 - 256; nw = 256; scale = 0.0625f; }
    else if (n0 < 768) { src = Wv; nb = n0 - 512; nw = 256; }
    else               { src = Wg; nb = n0 - 768; nw = 768; }
    const int j = tid & 15, kk = tid >> 4;
    #pragma unroll
    for (int r = 0; r < 16; ++r) {
        int k = r*16 + kk;
        tile[j][k] = src[(size_t)k*nw + nb + j] * scale;
    }
    __syncthreads();
    #pragma unroll
    for (int r = 0; r < 16; ++r) {
        float v = tile[r][tid];
        bf16 h, l; split_bf16(v, h, l);
        WhT[(size_t)(n0 + r)*256 + tid] = h;
        WlT[(size_t)(n0 + r)*256 + tid] = l;
    }
    if (tid < 16) {
        int n = n0 + tid;
        float bC;
        if (n < 256)        bC = bq[n];
        else if (n < 512)   bC = bk[n-256] * 0.0625f;
        else if (n < 768)   bC = bv[n-512];
        else if (n < 1024)  bC = bg[n-768] + input_bias[n-768];
        else                bC = bg[n-768];
        biasC[n] = bC;
    }
}

// ---------------- fused projection GEMM (m97 structure + T2 swizzle):
// 128x128 tile, BK=32, single-buffered 32KB LDS, swizzled staging + b128 reads.
// Uniform epilogue: val + biasC[gcol] -> plane store (no branches, no transcendentals).
__global__ __launch_bounds__(256, 4) void proj_gemm(
    const bf16* __restrict__ xh, const bf16* __restrict__ xl,
    const bf16* __restrict__ WhT, const bf16* __restrict__ WlT,
    const float* __restrict__ biasC,
    float* __restrict__ qP, float* __restrict__ kP, float* __restrict__ vP,
    float* __restrict__ liP, float* __restrict__ lfP, float* __restrict__ soP)
{
    __shared__ bf16 Ah[128*32];
    __shared__ bf16 Al[128*32];
    __shared__ bf16 Bh[128*32];
    __shared__ bf16 Bl[128*32];
    const int tid = threadIdx.x;
    const int w = tid >> 6, l = tid & 63;
    const int wr = w >> 1, wc = w & 1;
    const int m0 = blockIdx.x * 128;
    const int n0 = blockIdx.y * 128;
    const int lr = l & 15, lk = l >> 4;

    f32x4 acc[4][4] = {};

    for (int kt = 0; kt < 256; kt += 32) {
        #pragma unroll
        for (int p = 0; p < 2; ++p) {
            int e = p*2048 + tid*8;
            int row = e >> 5;
            int cb  = (e >> 3) & 3;
            int scol = ((cb ^ ((row >> 1) & 3)) << 3);
            size_t ga = (size_t)(m0 + row)*256 + kt + scol;
            size_t gb = (size_t)(n0 + row)*256 + kt + scol;
            GLD16(xh + ga, Ah + e);
            GLD16(xl + ga, Al + e);
            GLD16(WhT + gb, Bh + e);
            GLD16(WlT + gb, Bl + e);
        }
        __syncthreads();

        bf16x8 afh[4], afl[4], bfh[4], bfl[4];
        #pragma unroll
        for (int mi = 0; mi < 4; ++mi) {
            int row = wr*64 + mi*16 + lr;
            int slot = lk ^ ((row >> 1) & 3);
            afh[mi] = *(const bf16x8*)(Ah + row*32 + slot*8);
            afl[mi] = *(const bf16x8*)(Al + row*32 + slot*8);
        }
        #pragma unroll
        for (int ni = 0; ni < 4; ++ni) {
            int row = wc*64 + ni*16 + lr;
            int slot = lk ^ ((row >> 1) & 3);
            bfh[ni] = *(const bf16x8*)(Bh + row*32 + slot*8);
            bfl[ni] = *(const bf16x8*)(Bl + row*32 + slot*8);
        }
        #pragma unroll
        for (int ni = 0; ni < 4; ++ni)
            #pragma unroll
            for (int mi = 0; mi < 4; ++mi) {
                acc[mi][ni] = MFMA(afh[mi], bfh[ni], acc[mi][ni]);
                acc[mi][ni] = MFMA(afl[mi], bfh[ni], acc[mi][ni]);
                acc[mi][ni] = MFMA(afh[mi], bfl[ni], acc[mi][ni]);
            }
        __syncthreads();
    }

    const int seg = n0 >> 8;   // wg-uniform plane select
    float* dst = (seg == 0) ? qP : (seg == 1) ? kP : (seg == 2) ? vP
               : (seg == 3) ? liP : (seg == 4) ? lfP : soP;
    #pragma unroll
    for (int mi = 0; mi < 4; ++mi) {
        #pragma unroll
        for (int ni = 0; ni < 4; ++ni) {
            int gcol = n0 + wc*64 + ni*16 + lr;
            int c = gcol & 255;
            float bC = biasC[gcol];
            #pragma unroll
            for (int r = 0; r < 4; ++r) {
                int grow = m0 + wr*64 + mi*16 + lk*4 + r;
                dst[(size_t)grow*256 + c] = acc[mi][ni][r] + bC;
            }
        }
    }
}

// ---------------- fused chunk summary + Delta-M (activations computed inline):
__global__ __launch_bounds__(256) void s2_dm(
    const float* __restrict__ kP, const float* __restrict__ vP,
    const float* __restrict__ liP, const float* __restrict__ lfP,
    float* __restrict__ Csum, float* __restrict__ Mu, float* __restrict__ Bn,
    bf16* __restrict__ DM)
{
    __shared__ bf16 BTh[DMODEL][40], BTl[DMODEL][40];
    __shared__ bf16 KTh[DMODEL][40], KTl[DMODEL][40];
    const int tid = threadIdx.x;
    const int w = tid >> 6, l = tid & 63;
    const int b = blockIdx.x >> 6, c = blockIdx.x & 63;
    const size_t pb = ((size_t)b*T_LEN + (size_t)c*CH_L)*DMODEL;

    {
        float C = 0.f, mu = -3e38f;
        float val[CH_L];
        #pragma unroll
        for (int s = 0; s < CH_L; ++s) {
            size_t o = pb + (size_t)s*DMODEL + tid;
            C += nsoftplus_fast(lfP[o]);
            val[s] = 10.0f * tanh_fast(0.1f * liP[o]) - C;
            mu = fmaxf(mu, val[s]);
        }
        float bn = 0.f;
        #pragma unroll
        for (int s = 0; s < CH_L; ++s) {
            size_t o = pb + (size_t)s*DMODEL + tid;
            float e = __expf(val[s] - mu);
            float kv = kP[o];
            bn += e * kv;
            float bv = e * vP[o];
            bf16 h, lo; split_bf16(bv, h, lo);
            BTh[tid][s] = h; BTl[tid][s] = lo;
            bf16 kh, kl; split_bf16(kv, kh, kl);
            KTh[tid][s] = kh; KTl[tid][s] = kl;
        }
        size_t so = ((size_t)b*NCH + c)*DMODEL + tid;
        Csum[so] = C; Mu[so] = mu; Bn[so] = bn;
    }
    __syncthreads();

    const int lr = l & 15, lk = l >> 4;
    bf16x8 Ah[4], Al[4];
    #pragma unroll
    for (int it = 0; it < 4; ++it) {
        int row = w*64 + it*16 + lr;
        Ah[it] = *(const bf16x8*)&BTh[row][lk*8];
        Al[it] = *(const bf16x8*)&BTl[row][lk*8];
    }
    bf16* DMc = DM + (size_t)((size_t)b*NCH + c)*MSLOT;
    #pragma unroll
    for (int jt = 0; jt < 16; ++jt) {
        int jcol = jt*16 + lr;
        bf16x8 bh = *(const bf16x8*)&KTh[jcol][lk*8];
        bf16x8 bl = *(const bf16x8*)&KTl[jcol][lk*8];
        #pragma unroll
        for (int it = 0; it < 4; ++it) {
            f32x4 a = {0.f,0.f,0.f,0.f};
            a = MFMA(Ah[it], bh, a);
            a = MFMA(Al[it], bh, a);
            a = MFMA(Ah[it], bl, a);
            #pragma unroll
            for (int r = 0; r < 4; ++r)
                DMc[(size_t)(w*64 + it*16 + lk*4 + r)*DMODEL + jcol] = (bf16)a[r];
        }
    }
}

// ---------------- sequential compose of (m,n) boundary states across 64 chunks (tiny)
__global__ __launch_bounds__(256) void chunk_compose(
    const float* __restrict__ Csum, const float* __restrict__ Mu, const float* __restrict__ Bn,
    float* __restrict__ mIn, float* __restrict__ nIn, float* __restrict__ Th,
    float* __restrict__ Dd, float* __restrict__ Ee)
{
    const int b = blockIdx.x;
    const int j = threadIdx.x;
    float m = 0.f, n = 0.f;
    for (int c = 0; c < NCH; ++c) {
        size_t o = ((size_t)b*NCH + c)*DMODEL + j;
        mIn[o] = m; nIn[o] = n;
        float cs = Csum[o], mu = Mu[o], bn = Bn[o];
        float th = fmaxf(m, mu);
        Th[o] = th;
        float emu = __expf(mu - th);
        Dd[o] = __expf(m - th);
        Ee[o] = emu;
        n = __expf(m - th)*n + emu*bn;
        m = cs + th;
    }
}

// ---------------- compose M across chunks; 512 threads = 2 i-rows per block (1KB/step)
__global__ __launch_bounds__(512) void s3_compose(
    const float* __restrict__ Dd, const float* __restrict__ Ee, bf16* __restrict__ DM)
{
    const int b = blockIdx.x >> 7;
    const int i = ((blockIdx.x & 127) << 1) + (threadIdx.x >> 8);
    const int j = threadIdx.x & 255;
    float acc = 0.f;
    const size_t base = ((size_t)b*NCH)*MSLOT + (size_t)i*DMODEL + j;
    const size_t sb = (size_t)b*NCH*DMODEL + i;
    #pragma unroll 1
    for (int c = 0; c < NCH; c += 4) {
        float dm0 = (float)DM[base + (size_t)(c+0)*MSLOT];
        float dm1 = (float)DM[base + (size_t)(c+1)*MSLOT];
        float dm2 = (float)DM[base + (size_t)(c+2)*MSLOT];
        float dm3 = (float)DM[base + (size_t)(c+3)*MSLOT];
        float d0 = Dd[sb + (size_t)(c+0)*DMODEL], e0 = Ee[sb + (size_t)(c+0)*DMODEL];
        float d1 = Dd[sb + (size_t)(c+1)*DMODEL], e1 = Ee[sb + (size_t)(c+1)*DMODEL];
        float d2 = Dd[sb + (size_t)(c+2)*DMODEL], e2 = Ee[sb + (size_t)(c+2)*DMODEL];
        float d3 = Dd[sb + (size_t)(c+3)*DMODEL], e3 = Ee[sb + (size_t)(c+3)*DMODEL];
        if (c > 0) DM[base + (size_t)(c+0)*MSLOT] = (bf16)acc;
        acc = d0*acc + e0*dm0;
        DM[base + (size_t)(c+1)*MSLOT] = (bf16)acc;
        acc = d1*acc + e1*dm1;
        DM[base + (size_t)(c+2)*MSLOT] = (bf16)acc;
        acc = d2*acc + e2*dm2;
        DM[base + (size_t)(c+3)*MSLOT] = (bf16)acc;
        acc = d3*acc + e3*dm3;
    }
}

// ---------------- per-chunk output + fused RMSNorm (activations inline)
__global__ __launch_bounds__(256) void s4_chunk(
    const float* __restrict__ qP, const float* __restrict__ kP, const float* __restrict__ vP,
    const float* __restrict__ liP, const float* __restrict__ lfP, const float* __restrict__ soP,
    const float* __restrict__ mIn, const float* __restrict__ nIn, const float* __restrict__ Th,
    const bf16* __restrict__ DM, const float* __restrict__ norm_scale,
    float* __restrict__ out)
{
    __shared__ __align__(16) char kqbuf[33792];
    bf16 (*Kf)[264] = (bf16(*)[264])kqbuf;
    bf16 (*Qf)[264] = (bf16(*)[264])(kqbuf + 16896);
    float (*Hout)[264] = (float(*)[264])kqbuf;
    __shared__ bf16 F1L[CH_L][264];
    __shared__ __align__(16) bf16 BTh[DMODEL][40];
    __shared__ __align__(16) bf16 GT[CH_L][48];
    __shared__ float part[CH_L][4];
    __shared__ float denoms[CH_L];
    __shared__ float exL[DMODEL];

    const int tid = threadIdx.x;
    const int w = tid >> 6, l = tid & 63;
    const int b = blockIdx.x >> 6;
    const int c = blockIdx.x & 63;
    const size_t pb = ((size_t)b*T_LEN + (size_t)c*CH_L)*DMODEL;

    // phase 1: per-dim recurrences (thread = dim)
    const int i = tid;
    const size_t cbx = ((size_t)b*NCH + c)*DMODEL + i;
    const float thL = Th[cbx];
    const float mI = mIn[cbx];
    float P[CH_L];
    {
        float C = 0.f, mu = -3e38f, n = nIn[cbx], thp = mI;
        #pragma unroll
        for (int t = 0; t < CH_L; ++t) {
            size_t o = pb + (size_t)t*DMODEL + i;
            float lf = nsoftplus_fast(lfP[o]);
            float li = 10.0f * tanh_fast(0.1f * liP[o]);
            float kv = kP[o], qv = qP[o], vv = vP[o];
            C += lf;
            float vlc = li - C;
            mu = fmaxf(mu, vlc);
            float tht = fmaxf(mI, mu);
            float f = __expf(thp - tht);
            float iv = __expf(vlc - tht);
            n = f*n + iv*kv;
            thp = tht;
            P[t] = n * qv;
            Kf[t][i] = (bf16)kv;
            Qf[t][i] = (bf16)qv;
            F1L[t][i] = (bf16)__expf(mI - tht);
            BTh[i][t] = (bf16)(__expf(vlc - thL) * vv);
        }
        exL[i] = __expf(thL - mI);
    }
    // phase 2: wave-reduce P
    #pragma unroll
    for (int t = 0; t < CH_L; ++t) {
        float s = P[t];
        #pragma unroll
        for (int sh = 32; sh; sh >>= 1) s += __shfl_xor(s, sh);
        if (l == 0) part[t][w] = s;
    }
    __syncthreads();

    // phase 3a: denominators
    if (tid < CH_L)
        denoms[tid] = fmaxf(fabsf(part[tid][0] + part[tid][1] + part[tid][2] + part[tid][3]), 1e-6f);

    // phase 3b: G = K Q^T single-pass bf16
    {
        const int a = w & 1, bb = w >> 1;
        const int lr = l & 15, lk2 = l >> 4;
        if (a == 1 && bb == 0) {
            bf16x4 z = {(bf16)0.f, (bf16)0.f, (bf16)0.f, (bf16)0.f};
            *(bf16x4*)&GT[lr][16 + lk2*4] = z;
        } else {
            f32x4 g = {0.f,0.f,0.f,0.f};
            #pragma unroll
            for (int ks = 0; ks < 8; ++ks) {
                bf16x8 ah = *(const bf16x8*)&Kf[16*a  + lr][ks*32 + lk2*8];
                bf16x8 bh = *(const bf16x8*)&Qf[16*bb + lr][ks*32 + lk2*8];
                g = MFMA(ah, bh, g);
            }
            bf16x4 gv;
            #pragma unroll
            for (int r = 0; r < 4; ++r) {
                int s = 16*a + lk2*4 + r, t = 16*bb + lr;
                gv[r] = (s <= t) ? (bf16)g[r] : (bf16)0.f;
            }
            *(bf16x4*)&GT[16*bb + lr][16*a + lk2*4] = gv;
        }
    }
    __syncthreads();

    // phase 4: output GEMMs
    const int tt = w & 1;
    const int lr = l & 15, lk2 = l >> 4;
    const int trow = tt*16 + lr;
    f32x4 acc_a[8], acc_b[8];

    {
        bf16x8 gh = *(const bf16x8*)&GT[trow][lk2*8];
        #pragma unroll
        for (int it = 0; it < 8; ++it) {
            int irow = ((w>>1)*8 + it)*16 + lr;
            bf16x8 bb2 = *(const bf16x8*)&BTh[irow][lk2*8];
            f32x4 a = {0.f,0.f,0.f,0.f};
            acc_a[it] = MFMA(gh, bb2, a);
        }
    }
    #pragma unroll
    for (int it = 0; it < 8; ++it) acc_b[it] = (f32x4){0.f,0.f,0.f,0.f};
    if (c > 0) {
        const u16* Mbase = (const u16*)DM + (size_t)((size_t)b*NCH + c)*MSLOT;
        #pragma unroll
        for (int ks = 0; ks < 8; ++ks) {
            bf16x8 qh = *(const bf16x8*)&Qf[trow][ks*32 + lk2*8];
            #pragma unroll
            for (int it = 0; it < 8; ++it) {
                int irow = ((w>>1)*8 + it)*16 + lr;
                union { u16x8 u; bf16x8 h; } M8;
                M8.u = *(const u16x8*)(Mbase + (size_t)irow*DMODEL + ks*32 + lk2*8);
                acc_b[it] = MFMA(qh, M8.h, acc_b[it]);
            }
        }
    }
    __syncthreads();

    // epilogue part 1
    #pragma unroll
    for (int it = 0; it < 8; ++it) {
        int icol = ((w>>1)*8 + it)*16 + lr;
        float ex = exL[icol];
        #pragma unroll
        for (int r = 0; r < 4; ++r) {
            int t = tt*16 + lk2*4 + r;
            float F1 = (float)F1L[t][icol];
            float h = F1 * (acc_b[it][r] + ex * acc_a[it][r]);
            size_t o = pb + (size_t)t*DMODEL + icol;
            Hout[t][icol] = sigmoid_fast(soP[o]) * h / denoms[t];
        }
    }
    __syncthreads();
    // epilogue part 2: fused RMSNorm
    #pragma unroll
    for (int r = 0; r < 8; ++r) {
        int t = w*8 + r;
        f32x4 hv = *(const f32x4*)&Hout[t][l*4];
        float ss = hv[0]*hv[0] + hv[1]*hv[1] + hv[2]*hv[2] + hv[3]*hv[3];
        #pragma unroll
        for (int sh = 32; sh; sh >>= 1) ss += __shfl_xor(ss, sh);
        float rinv = rsqrtf(ss * (1.0f/256.0f) + 1e-8f);
        f32x4 ns = *(const f32x4*)(norm_scale + l*4);
        f32x4 o4;
        #pragma unroll
        for (int e = 0; e < 4; ++e) o4[e] = hv[e] * rinv * ns[e];
        *(f32x4*)(out + pb + (size_t)t*DMODEL + l*4) = o4;
    }
}

extern "C" void kernel_launch(void* const* d_in, const int* in_sizes, int n_in,
                              void* d_out, int out_size, void* d_ws, size_t ws_size,
                              hipStream_t stream) {
    const float* x          = (const float*)d_in[0];
    const float* Wq         = (const float*)d_in[1];
    const float* bq         = (const float*)d_in[2];
    const float* Wk         = (const float*)d_in[3];
    const float* bk         = (const float*)d_in[4];
    const float* Wv         = (const float*)d_in[5];
    const float* bv         = (const float*)d_in[6];
    const float* Wg         = (const float*)d_in[7];
    const float* bg         = (const float*)d_in[8];
    const float* input_bias = (const float*)d_in[9];
    const float* norm_scale = (const float*)d_in[10];
    float* out = (float*)d_out;

    float* qP   = (float*)d_ws;
    float* kP   = qP  + PLANE;
    float* vP   = kP  + PLANE;
    float* liP  = vP  + PLANE;
    float* lfP  = liP + PLANE;
    float* soP  = lfP + PLANE;
    float* Csum = soP + PLANE;
    float* Mu   = Csum + SUMSZ;
    float* Bn   = Mu   + SUMSZ;
    float* mIn  = Bn   + SUMSZ;
    float* nIn  = mIn  + SUMSZ;
    float* Th   = nIn  + SUMSZ;
    float* Dd   = Th   + SUMSZ;
    float* Ee   = Dd   + SUMSZ;
    float* biasC = Ee  + SUMSZ;                       // 1536 floats
    bf16*  DM   = (bf16*)(biasC + 2048);              // 4*64*65536 bf16 = 32 MiB
    bf16*  WhT  = DM + (size_t)BATCH*NCH*MSLOT;
    bf16*  WlT  = WhT + 1536*256;
    bf16*  xh   = WlT + 1536*256;
    bf16*  xl   = xh + PLANE;

    pack_w<<<dim3(96), dim3(256), 0, stream>>>(Wq, Wk, Wv, Wg, bq, bk, bv, bg, input_bias,
                                               WhT, WlT, biasC);
    split_x<<<dim3(1024), dim3(256), 0, stream>>>(x, xh, xl);
    proj_gemm<<<dim3(64, 12), dim3(256), 0, stream>>>(xh, xl, WhT, WlT, biasC,
                                                      qP, kP, vP, liP, lfP, soP);
    s2_dm<<<dim3(BATCH*NCH), dim3(256), 0, stream>>>(kP, vP, liP, lfP, Csum, Mu, Bn, DM);
    chunk_compose<<<dim3(BATCH), dim3(256), 0, stream>>>(Csum, Mu, Bn, mIn, nIn, Th, Dd, Ee);
    s3_compose<<<dim3(BATCH*128), dim3(512), 0, stream>>>(Dd, Ee, DM);
    s4_chunk<<<dim3(BATCH*NCH), dim3(256), 0, stream>>>(qP, kP, vP, liP, lfP, soP,
                                                        mIn, nIn, Th, DM, norm_scale, out);
}

// Round 13
// 101.865 us; speedup vs baseline: 1.5374x; 1.0822x over previous
//
#include <hip/hip_runtime.h>
#include <hip/hip_bf16.h>
#include <math.h>

#define T_LEN 2048
#define BATCH 4
#define DMODEL 256
#define MROWS (BATCH*T_LEN)
#define PLANE (MROWS*DMODEL)
#define CH_L 32
#define NCH  (T_LEN/CH_L)          // 64
#define SUMSZ (BATCH*NCH*DMODEL)   // 65536
#define MSLOT (DMODEL*DMODEL)      // 65536

typedef __bf16 bf16;
typedef __bf16 bf16x4 __attribute__((ext_vector_type(4)));
typedef __bf16 bf16x8 __attribute__((ext_vector_type(8)));
typedef _Float16 f16;
typedef _Float16 f16x8 __attribute__((ext_vector_type(8)));
typedef float  f32x4  __attribute__((ext_vector_type(4)));
typedef unsigned short u16;
typedef u16 u16x8 __attribute__((ext_vector_type(8)));
typedef unsigned int u32;

#define MFMA(a,b,c)   __builtin_amdgcn_mfma_f32_16x16x32_bf16(a, b, c, 0, 0, 0)
#define MFMA16(a,b,c) __builtin_amdgcn_mfma_f32_16x16x32_f16(a, b, c, 0, 0, 0)

__device__ __forceinline__ void split_bf16(float x, bf16& hi, bf16& lo) {
    hi = (bf16)x;
    lo = (bf16)(x - (float)hi);
}

// fast transcendentals (hardware v_exp_f32 based)
__device__ __forceinline__ float tanh_fast(float z) {
    z = fminf(fmaxf(z, -15.f), 15.f);
    float e = __expf(2.f * z);
    return (e - 1.f) / (e + 1.f);
}
__device__ __forceinline__ float nsoftplus_fast(float y) {   // -softplus(y)
    return -(fmaxf(y, 0.f) + __logf(1.f + __expf(-fabsf(y))));
}
__device__ __forceinline__ float sigmoid_fast(float y) {
    return 1.f / (1.f + __expf(-y));
}

#define GLD16(SRC, DST) __builtin_amdgcn_global_load_lds( \
    (const __attribute__((address_space(1))) void*)(SRC), \
    (__attribute__((address_space(3))) void*)(DST), 16, 0, 0)

// ---------------- convert x to f16 plane (grid = PLANE/2048 = 1024)
__global__ __launch_bounds__(256) void split_x(const float* __restrict__ x,
                                               f16* __restrict__ xf) {
    int i = (blockIdx.x*256 + threadIdx.x) * 8;
    f32x4 a = *(const f32x4*)(x + i);
    f32x4 b = *(const f32x4*)(x + i + 4);
    f16x8 h;
    #pragma unroll
    for (int e = 0; e < 4; ++e) {
        h[e]   = (f16)a[e];
        h[4+e] = (f16)b[e];
    }
    *(f16x8*)(xf + i) = h;
}

// ---------------- pack weights (coalesced LDS transpose, f16) + fused scale/bias fold
__global__ __launch_bounds__(256) void pack_w(const float* __restrict__ Wq,
                                              const float* __restrict__ Wk,
                                              const float* __restrict__ Wv,
                                              const float* __restrict__ Wg,
                                              const float* __restrict__ bq,
                                              const float* __restrict__ bk,
                                              const float* __restrict__ bv,
                                              const float* __restrict__ bg,
                                              const float* __restrict__ input_bias,
                                              f16* __restrict__ Wf,
                                              float* __restrict__ biasC) {
    __shared__ float tile[16][260];   // [n-local][k]
    const int tid = threadIdx.x;
    const int n0 = blockIdx.x * 16;
    const float* src; int nb, nw;
    float scale = 1.0f;
    if (n0 < 256)      { src = Wq; nb = n0;       nw = 256; }
    else if (n0 < 512) { src = Wk; nb = n0 - 256; nw = 256; scale = 0.0625f; }
    else if (n0 < 768) { src = Wv; nb = n0 - 512; nw = 256; }
    else               { src = Wg; nb = n0 - 768; nw = 768; }
    const int j = tid & 15, kk = tid >> 4;
    #pragma unroll
    for (int r = 0; r < 16; ++r) {
        int k = r*16 + kk;
        tile[j][k] = src[(size_t)k*nw + nb + j] * scale;
    }
    __syncthreads();
    #pragma unroll
    for (int r = 0; r < 16; ++r)
        Wf[(size_t)(n0 + r)*256 + tid] = (f16)tile[r][tid];
    if (tid < 16) {
        int n = n0 + tid;
        float bC;
        if (n < 256)        bC = bq[n];
        else if (n < 512)   bC = bk[n-256] * 0.0625f;
        else if (n < 768)   bC = bv[n-512];
        else if (n < 1024)  bC = bg[n-768] + input_bias[n-768];
        else                bC = bg[n-768];
        biasC[n] = bC;
    }
}

// ---------------- fused projection GEMM: f16 single-pass (m97 structure + T2 swizzle):
// 128x128 tile, BK=32, single-buffered 16KB LDS, 16 MFMA/K-step, uniform epilogue.
__global__ __launch_bounds__(256, 4) void proj_gemm(
    const f16* __restrict__ xf, const f16* __restrict__ Wf,
    const float* __restrict__ biasC,
    float* __restrict__ qP, float* __restrict__ kP, float* __restrict__ vP,
    float* __restrict__ liP, float* __restrict__ lfP, float* __restrict__ soP)
{
    __shared__ f16 Af[128*32];
    __shared__ f16 Bf[128*32];
    const int tid = threadIdx.x;
    const int w = tid >> 6, l = tid & 63;
    const int wr = w >> 1, wc = w & 1;
    const int m0 = blockIdx.x * 128;
    const int n0 = blockIdx.y * 128;
    const int lr = l & 15, lk = l >> 4;

    f32x4 acc[4][4] = {};

    for (int kt = 0; kt < 256; kt += 32) {
        #pragma unroll
        for (int p = 0; p < 2; ++p) {
            int e = p*2048 + tid*8;
            int row = e >> 5;
            int cb  = (e >> 3) & 3;
            int scol = ((cb ^ ((row >> 1) & 3)) << 3);
            GLD16(xf + (size_t)(m0 + row)*256 + kt + scol, Af + e);
            GLD16(Wf + (size_t)(n0 + row)*256 + kt + scol, Bf + e);
        }
        __syncthreads();

        f16x8 af[4], bf[4];
        #pragma unroll
        for (int mi = 0; mi < 4; ++mi) {
            int row = wr*64 + mi*16 + lr;
            int slot = lk ^ ((row >> 1) & 3);
            af[mi] = *(const f16x8*)(Af + row*32 + slot*8);
        }
        #pragma unroll
        for (int ni = 0; ni < 4; ++ni) {
            int row = wc*64 + ni*16 + lr;
            int slot = lk ^ ((row >> 1) & 3);
            bf[ni] = *(const f16x8*)(Bf + row*32 + slot*8);
        }
        #pragma unroll
        for (int ni = 0; ni < 4; ++ni)
            #pragma unroll
            for (int mi = 0; mi < 4; ++mi)
                acc[mi][ni] = MFMA16(af[mi], bf[ni], acc[mi][ni]);
        __syncthreads();
    }

    const int seg = n0 >> 8;   // wg-uniform plane select
    float* dst = (seg == 0) ? qP : (seg == 1) ? kP : (seg == 2) ? vP
               : (seg == 3) ? liP : (seg == 4) ? lfP : soP;
    #pragma unroll
    for (int mi = 0; mi < 4; ++mi) {
        #pragma unroll
        for (int ni = 0; ni < 4; ++ni) {
            int gcol = n0 + wc*64 + ni*16 + lr;
            int c = gcol & 255;
            float bC = biasC[gcol];
            #pragma unroll
            for (int r = 0; r < 4; ++r) {
                int grow = m0 + wr*64 + mi*16 + lk*4 + r;
                dst[(size_t)grow*256 + c] = acc[mi][ni][r] + bC;
            }
        }
    }
}

// ---------------- fused chunk summary + Delta-M (activations computed inline):
__global__ __launch_bounds__(256) void s2_dm(
    const float* __restrict__ kP, const float* __restrict__ vP,
    const float* __restrict__ liP, const float* __restrict__ lfP,
    float* __restrict__ Csum, float* __restrict__ Mu, float* __restrict__ Bn,
    bf16* __restrict__ DM)
{
    __shared__ bf16 BTh[DMODEL][40], BTl[DMODEL][40];
    __shared__ bf16 KTh[DMODEL][40], KTl[DMODEL][40];
    const int tid = threadIdx.x;
    const int w = tid >> 6, l = tid & 63;
    const int b = blockIdx.x >> 6, c = blockIdx.x & 63;
    const size_t pb = ((size_t)b*T_LEN + (size_t)c*CH_L)*DMODEL;

    {
        float C = 0.f, mu = -3e38f;
        float val[CH_L];
        #pragma unroll
        for (int s = 0; s < CH_L; ++s) {
            size_t o = pb + (size_t)s*DMODEL + tid;
            C += nsoftplus_fast(lfP[o]);
            val[s] = 10.0f * tanh_fast(0.1f * liP[o]) - C;
            mu = fmaxf(mu, val[s]);
        }
        float bn = 0.f;
        #pragma unroll
        for (int s = 0; s < CH_L; ++s) {
            size_t o = pb + (size_t)s*DMODEL + tid;
            float e = __expf(val[s] - mu);
            float kv = kP[o];
            bn += e * kv;
            float bv = e * vP[o];
            bf16 h, lo; split_bf16(bv, h, lo);
            BTh[tid][s] = h; BTl[tid][s] = lo;
            bf16 kh, kl; split_bf16(kv, kh, kl);
            KTh[tid][s] = kh; KTl[tid][s] = kl;
        }
        size_t so = ((size_t)b*NCH + c)*DMODEL + tid;
        Csum[so] = C; Mu[so] = mu; Bn[so] = bn;
    }
    __syncthreads();

    const int lr = l & 15, lk = l >> 4;
    bf16x8 Ah[4], Al[4];
    #pragma unroll
    for (int it = 0; it < 4; ++it) {
        int row = w*64 + it*16 + lr;
        Ah[it] = *(const bf16x8*)&BTh[row][lk*8];
        Al[it] = *(const bf16x8*)&BTl[row][lk*8];
    }
    bf16* DMc = DM + (size_t)((size_t)b*NCH + c)*MSLOT;
    #pragma unroll
    for (int jt = 0; jt < 16; ++jt) {
        int jcol = jt*16 + lr;
        bf16x8 bh = *(const bf16x8*)&KTh[jcol][lk*8];
        bf16x8 bl = *(const bf16x8*)&KTl[jcol][lk*8];
        #pragma unroll
        for (int it = 0; it < 4; ++it) {
            f32x4 a = {0.f,0.f,0.f,0.f};
            a = MFMA(Ah[it], bh, a);
            a = MFMA(Al[it], bh, a);
            a = MFMA(Ah[it], bl, a);
            #pragma unroll
            for (int r = 0; r < 4; ++r)
                DMc[(size_t)(w*64 + it*16 + lk*4 + r)*DMODEL + jcol] = (bf16)a[r];
        }
    }
}

// ---------------- sequential compose of (m,n) boundary states (batch-4 prefetched)
__global__ __launch_bounds__(256) void chunk_compose(
    const float* __restrict__ Csum, const float* __restrict__ Mu, const float* __restrict__ Bn,
    float* __restrict__ mIn, float* __restrict__ nIn, float* __restrict__ Th,
    float* __restrict__ Dd, float* __restrict__ Ee)
{
    const int b = blockIdx.x;
    const int j = threadIdx.x;
    float m = 0.f, n = 0.f;
    #pragma unroll 1
    for (int c = 0; c < NCH; c += 4) {
        size_t o0 = ((size_t)b*NCH + c)*DMODEL + j;
        float cs0 = Csum[o0],            mu0 = Mu[o0],            bn0 = Bn[o0];
        float cs1 = Csum[o0 + DMODEL],   mu1 = Mu[o0 + DMODEL],   bn1 = Bn[o0 + DMODEL];
        float cs2 = Csum[o0 + 2*DMODEL], mu2 = Mu[o0 + 2*DMODEL], bn2 = Bn[o0 + 2*DMODEL];
        float cs3 = Csum[o0 + 3*DMODEL], mu3 = Mu[o0 + 3*DMODEL], bn3 = Bn[o0 + 3*DMODEL];
        #define STEP(CS, MUv, BNv, OFF) { \
            mIn[o0 + (OFF)] = m; nIn[o0 + (OFF)] = n; \
            float th = fmaxf(m, MUv); \
            Th[o0 + (OFF)] = th; \
            float emu = __expf(MUv - th); \
            float d = __expf(m - th); \
            Dd[o0 + (OFF)] = d; Ee[o0 + (OFF)] = emu; \
            n = d*n + emu*(BNv); \
            m = (CS) + th; }
        STEP(cs0, mu0, bn0, 0)
        STEP(cs1, mu1, bn1, DMODEL)
        STEP(cs2, mu2, bn2, 2*DMODEL)
        STEP(cs3, mu3, bn3, 3*DMODEL)
        #undef STEP
    }
}

// ---------------- compose M across chunks; 512 threads = 2 i-rows per block (1KB/step)
__global__ __launch_bounds__(512) void s3_compose(
    const float* __restrict__ Dd, const float* __restrict__ Ee, bf16* __restrict__ DM)
{
    const int b = blockIdx.x >> 7;
    const int i = ((blockIdx.x & 127) << 1) + (threadIdx.x >> 8);
    const int j = threadIdx.x & 255;
    float acc = 0.f;
    const size_t base = ((size_t)b*NCH)*MSLOT + (size_t)i*DMODEL + j;
    const size_t sb = (size_t)b*NCH*DMODEL + i;
    #pragma unroll 1
    for (int c = 0; c < NCH; c += 4) {
        float dm0 = (float)DM[base + (size_t)(c+0)*MSLOT];
        float dm1 = (float)DM[base + (size_t)(c+1)*MSLOT];
        float dm2 = (float)DM[base + (size_t)(c+2)*MSLOT];
        float dm3 = (float)DM[base + (size_t)(c+3)*MSLOT];
        float d0 = Dd[sb + (size_t)(c+0)*DMODEL], e0 = Ee[sb + (size_t)(c+0)*DMODEL];
        float d1 = Dd[sb + (size_t)(c+1)*DMODEL], e1 = Ee[sb + (size_t)(c+1)*DMODEL];
        float d2 = Dd[sb + (size_t)(c+2)*DMODEL], e2 = Ee[sb + (size_t)(c+2)*DMODEL];
        float d3 = Dd[sb + (size_t)(c+3)*DMODEL], e3 = Ee[sb + (size_t)(c+3)*DMODEL];
        if (c > 0) DM[base + (size_t)(c+0)*MSLOT] = (bf16)acc;
        acc = d0*acc + e0*dm0;
        DM[base + (size_t)(c+1)*MSLOT] = (bf16)acc;
        acc = d1*acc + e1*dm1;
        DM[base + (size_t)(c+2)*MSLOT] = (bf16)acc;
        acc = d2*acc + e2*dm2;
        DM[base + (size_t)(c+3)*MSLOT] = (bf16)acc;
        acc = d3*acc + e3*dm3;
    }
}

// ---------------- per-chunk output + fused RMSNorm (activations inline)
__global__ __launch_bounds__(256) void s4_chunk(
    const float* __restrict__ qP, const float* __restrict__ kP, const float* __restrict__ vP,
    const float* __restrict__ liP, const float* __restrict__ lfP, const float* __restrict__ soP,
    const float* __restrict__ mIn, const float* __restrict__ nIn, const float* __restrict__ Th,
    const bf16* __restrict__ DM, const float* __restrict__ norm_scale,
    float* __restrict__ out)
{
    __shared__ __align__(16) char kqbuf[33792];
    bf16 (*Kf)[264] = (bf16(*)[264])kqbuf;
    bf16 (*Qf)[264] = (bf16(*)[264])(kqbuf + 16896);
    float (*Hout)[264] = (float(*)[264])kqbuf;
    __shared__ bf16 F1L[CH_L][264];
    __shared__ __align__(16) bf16 BTh[DMODEL][40];
    __shared__ __align__(16) bf16 GT[CH_L][48];
    __shared__ float part[CH_L][4];
    __shared__ float denoms[CH_L];
    __shared__ float exL[DMODEL];

    const int tid = threadIdx.x;
    const int w = tid >> 6, l = tid & 63;
    const int b = blockIdx.x >> 6;
    const int c = blockIdx.x & 63;
    const size_t pb = ((size_t)b*T_LEN + (size_t)c*CH_L)*DMODEL;

    // phase 1: per-dim recurrences (thread = dim)
    const int i = tid;
    const size_t cbx = ((size_t)b*NCH + c)*DMODEL + i;
    const float thL = Th[cbx];
    const float mI = mIn[cbx];
    float P[CH_L];
    {
        float C = 0.f, mu = -3e38f, n = nIn[cbx], thp = mI;
        #pragma unroll
        for (int t = 0; t < CH_L; ++t) {
            size_t o = pb + (size_t)t*DMODEL + i;
            float lf = nsoftplus_fast(lfP[o]);
            float li = 10.0f * tanh_fast(0.1f * liP[o]);
            float kv = kP[o], qv = qP[o], vv = vP[o];
            C += lf;
            float vlc = li - C;
            mu = fmaxf(mu, vlc);
            float tht = fmaxf(mI, mu);
            float f = __expf(thp - tht);
            float iv = __expf(vlc - tht);
            n = f*n + iv*kv;
            thp = tht;
            P[t] = n * qv;
            Kf[t][i] = (bf16)kv;
            Qf[t][i] = (bf16)qv;
            F1L[t][i] = (bf16)__expf(mI - tht);
            BTh[i][t] = (bf16)(__expf(vlc - thL) * vv);
        }
        exL[i] = __expf(thL - mI);
    }
    // phase 2: wave-reduce P
    #pragma unroll
    for (int t = 0; t < CH_L; ++t) {
        float s = P[t];
        #pragma unroll
        for (int sh = 32; sh; sh >>= 1) s += __shfl_xor(s, sh);
        if (l == 0) part[t][w] = s;
    }
    __syncthreads();

    // phase 3a: denominators
    if (tid < CH_L)
        denoms[tid] = fmaxf(fabsf(part[tid][0] + part[tid][1] + part[tid][2] + part[tid][3]), 1e-6f);

    // phase 3b: G = K Q^T single-pass bf16
    {
        const int a = w & 1, bb = w >> 1;
        const int lr = l & 15, lk2 = l >> 4;
        if (a == 1 && bb == 0) {
            bf16x4 z = {(bf16)0.f, (bf16)0.f, (bf16)0.f, (bf16)0.f};
            *(bf16x4*)&GT[lr][16 + lk2*4] = z;
        } else {
            f32x4 g = {0.f,0.f,0.f,0.f};
            #pragma unroll
            for (int ks = 0; ks < 8; ++ks) {
                bf16x8 ah = *(const bf16x8*)&Kf[16*a  + lr][ks*32 + lk2*8];
                bf16x8 bh = *(const bf16x8*)&Qf[16*bb + lr][ks*32 + lk2*8];
                g = MFMA(ah, bh, g);
            }
            bf16x4 gv;
            #pragma unroll
            for (int r = 0; r < 4; ++r) {
                int s = 16*a + lk2*4 + r, t = 16*bb + lr;
                gv[r] = (s <= t) ? (bf16)g[r] : (bf16)0.f;
            }
            *(bf16x4*)&GT[16*bb + lr][16*a + lk2*4] = gv;
        }
    }
    __syncthreads();

    // phase 4: output GEMMs
    const int tt = w & 1;
    const int lr = l & 15, lk2 = l >> 4;
    const int trow = tt*16 + lr;
    f32x4 acc_a[8], acc_b[8];

    {
        bf16x8 gh = *(const bf16x8*)&GT[trow][lk2*8];
        #pragma unroll
        for (int it = 0; it < 8; ++it) {
            int irow = ((w>>1)*8 + it)*16 + lr;
            bf16x8 bb2 = *(const bf16x8*)&BTh[irow][lk2*8];
            f32x4 a = {0.f,0.f,0.f,0.f};
            acc_a[it] = MFMA(gh, bb2, a);
        }
    }
    #pragma unroll
    for (int it = 0; it < 8; ++it) acc_b[it] = (f32x4){0.f,0.f,0.f,0.f};
    if (c > 0) {
        const u16* Mbase = (const u16*)DM + (size_t)((size_t)b*NCH + c)*MSLOT;
        #pragma unroll
        for (int ks = 0; ks < 8; ++ks) {
            bf16x8 qh = *(const bf16x8*)&Qf[trow][ks*32 + lk2*8];
            #pragma unroll
            for (int it = 0; it < 8; ++it) {
                int irow = ((w>>1)*8 + it)*16 + lr;
                union { u16x8 u; bf16x8 h; } M8;
                M8.u = *(const u16x8*)(Mbase + (size_t)irow*DMODEL + ks*32 + lk2*8);
                acc_b[it] = MFMA(qh, M8.h, acc_b[it]);
            }
        }
    }
    __syncthreads();

    // epilogue part 1
    #pragma unroll
    for (int it = 0; it < 8; ++it) {
        int icol = ((w>>1)*8 + it)*16 + lr;
        float ex = exL[icol];
        #pragma unroll
        for (int r = 0; r < 4; ++r) {
            int t = tt*16 + lk2*4 + r;
            float F1 = (float)F1L[t][icol];
            float h = F1 * (acc_b[it][r] + ex * acc_a[it][r]);
            size_t o = pb + (size_t)t*DMODEL + icol;
            Hout[t][icol] = sigmoid_fast(soP[o]) * h / denoms[t];
        }
    }
    __syncthreads();
    // epilogue part 2: fused RMSNorm
    #pragma unroll
    for (int r = 0; r < 8; ++r) {
        int t = w*8 + r;
        f32x4 hv = *(const f32x4*)&Hout[t][l*4];
        float ss = hv[0]*hv[0] + hv[1]*hv[1] + hv[2]*hv[2] + hv[3]*hv[3];
        #pragma unroll
        for (int sh = 32; sh; sh >>= 1) ss += __shfl_xor(ss, sh);
        float rinv = rsqrtf(ss * (1.0f/256.0f) + 1e-8f);
        f32x4 ns = *(const f32x4*)(norm_scale + l*4);
        f32x4 o4;
        #pragma unroll
        for (int e = 0; e < 4; ++e) o4[e] = hv[e] * rinv * ns[e];
        *(f32x4*)(out + pb + (size_t)t*DMODEL + l*4) = o4;
    }
}

extern "C" void kernel_launch(void* const* d_in, const int* in_sizes, int n_in,
                              void* d_out, int out_size, void* d_ws, size_t ws_size,
                              hipStream_t stream) {
    const float* x          = (const float*)d_in[0];
    const float* Wq         = (const float*)d_in[1];
    const float* bq         = (const float*)d_in[2];
    const float* Wk         = (const float*)d_in[3];
    const float* bk         = (const float*)d_in[4];
    const float* Wv         = (const float*)d_in[5];
    const float* bv         = (const float*)d_in[6];
    const float* Wg         = (const float*)d_in[7];
    const float* bg         = (const float*)d_in[8];
    const float* input_bias = (const float*)d_in[9];
    const float* norm_scale = (const float*)d_in[10];
    float* out = (float*)d_out;

    float* qP   = (float*)d_ws;
    float* kP   = qP  + PLANE;
    float* vP   = kP  + PLANE;
    float* liP  = vP  + PLANE;
    float* lfP  = liP + PLANE;
    float* soP  = lfP + PLANE;
    float* Csum = soP + PLANE;
    float* Mu   = Csum + SUMSZ;
    float* Bn   = Mu   + SUMSZ;
    float* mIn  = Bn   + SUMSZ;
    float* nIn  = mIn  + SUMSZ;
    float* Th   = nIn  + SUMSZ;
    float* Dd   = Th   + SUMSZ;
    float* Ee   = Dd   + SUMSZ;
    float* biasC = Ee  + SUMSZ;                       // 1536 floats
    bf16*  DM   = (bf16*)(biasC + 2048);              // 4*64*65536 bf16 = 32 MiB
    f16*   Wf   = (f16*)(DM + (size_t)BATCH*NCH*MSLOT);
    f16*   xf   = Wf + 1536*256;

    pack_w<<<dim3(96), dim3(256), 0, stream>>>(Wq, Wk, Wv, Wg, bq, bk, bv, bg, input_bias,
                                               Wf, biasC);
    split_x<<<dim3(1024), dim3(256), 0, stream>>>(x, xf);
    proj_gemm<<<dim3(64, 12), dim3(256), 0, stream>>>(xf, Wf, biasC,
                                                      qP, kP, vP, liP, lfP, soP);
    s2_dm<<<dim3(BATCH*NCH), dim3(256), 0, stream>>>(kP, vP, liP, lfP, Csum, Mu, Bn, DM);
    chunk_compose<<<dim3(BATCH), dim3(256), 0, stream>>>(Csum, Mu, Bn, mIn, nIn, Th, Dd, Ee);
    s3_compose<<<dim3(BATCH*128), dim3(512), 0, stream>>>(Dd, Ee, DM);
    s4_chunk<<<dim3(BATCH*NCH), dim3(256), 0, stream>>>(qP, kP, vP, liP, lfP, soP,
                                                        mIn, nIn, Th, DM, norm_scale, out);
}

// Round 15
// 94.927 us; speedup vs baseline: 1.6497x; 1.0731x over previous
//
#include <hip/hip_runtime.h>
#include <hip/hip_bf16.h>
#include <math.h>

#define T_LEN 2048
#define BATCH 4
#define DMODEL 256
#define MROWS (BATCH*T_LEN)
#define PLANE (MROWS*DMODEL)
#define CH_L 32
#define NCH  (T_LEN/CH_L)          // 64
#define SUMSZ (BATCH*NCH*DMODEL)   // 65536
#define MSLOT (DMODEL*DMODEL)      // 65536

typedef __bf16 bf16;
typedef __bf16 bf16x4 __attribute__((ext_vector_type(4)));
typedef __bf16 bf16x8 __attribute__((ext_vector_type(8)));
typedef _Float16 f16;
typedef _Float16 f16x8 __attribute__((ext_vector_type(8)));
typedef float  f32x4  __attribute__((ext_vector_type(4)));
typedef unsigned short u16;
typedef u16 u16x8 __attribute__((ext_vector_type(8)));
typedef unsigned int u32;

#define MFMA(a,b,c)   __builtin_amdgcn_mfma_f32_16x16x32_bf16(a, b, c, 0, 0, 0)
#define MFMA16(a,b,c) __builtin_amdgcn_mfma_f32_16x16x32_f16(a, b, c, 0, 0, 0)

__device__ __forceinline__ void split_bf16(float x, bf16& hi, bf16& lo) {
    hi = (bf16)x;
    lo = (bf16)(x - (float)hi);
}

// fast transcendentals (hardware v_exp_f32 based)
__device__ __forceinline__ float tanh_fast(float z) {
    z = fminf(fmaxf(z, -15.f), 15.f);
    float e = __expf(2.f * z);
    return (e - 1.f) / (e + 1.f);
}
__device__ __forceinline__ float nsoftplus_fast(float y) {   // -softplus(y)
    return -(fmaxf(y, 0.f) + __logf(1.f + __expf(-fabsf(y))));
}
__device__ __forceinline__ float sigmoid_fast(float y) {
    return 1.f / (1.f + __expf(-y));
}

#define GLD16(SRC, DST) __builtin_amdgcn_global_load_lds( \
    (const __attribute__((address_space(1))) void*)(SRC), \
    (__attribute__((address_space(3))) void*)(DST), 16, 0, 0)

// ---------------- convert x to f16 plane (grid = PLANE/2048 = 1024)
__global__ __launch_bounds__(256) void split_x(const float* __restrict__ x,
                                               f16* __restrict__ xf) {
    int i = (blockIdx.x*256 + threadIdx.x) * 8;
    f32x4 a = *(const f32x4*)(x + i);
    f32x4 b = *(const f32x4*)(x + i + 4);
    f16x8 h;
    #pragma unroll
    for (int e = 0; e < 4; ++e) {
        h[e]   = (f16)a[e];
        h[4+e] = (f16)b[e];
    }
    *(f16x8*)(xf + i) = h;
}

// ---------------- pack weights (coalesced LDS transpose, f16) + fused scale/bias fold
__global__ __launch_bounds__(256) void pack_w(const float* __restrict__ Wq,
                                              const float* __restrict__ Wk,
                                              const float* __restrict__ Wv,
                                              const float* __restrict__ Wg,
                                              const float* __restrict__ bq,
                                              const float* __restrict__ bk,
                                              const float* __restrict__ bv,
                                              const float* __restrict__ bg,
                                              const float* __restrict__ input_bias,
                                              f16* __restrict__ Wf,
                                              float* __restrict__ biasC) {
    __shared__ float tile[16][260];   // [n-local][k]
    const int tid = threadIdx.x;
    const int n0 = blockIdx.x * 16;
    const float* src; int nb, nw;
    float scale = 1.0f;
    if (n0 < 256)      { src = Wq; nb = n0;       nw = 256; }
    else if (n0 < 512) { src = Wk; nb = n0 - 256; nw = 256; scale = 0.0625f; }
    else if (n0 < 768) { src = Wv; nb = n0 - 512; nw = 256; }
    else               { src = Wg; nb = n0 - 768; nw = 768; }
    const int j = tid & 15, kk = tid >> 4;
    #pragma unroll
    for (int r = 0; r < 16; ++r) {
        int k = r*16 + kk;
        tile[j][k] = src[(size_t)k*nw + nb + j] * scale;
    }
    __syncthreads();
    #pragma unroll
    for (int r = 0; r < 16; ++r)
        Wf[(size_t)(n0 + r)*256 + tid] = (f16)tile[r][tid];
    if (tid < 16) {
        int n = n0 + tid;
        float bC;
        if (n < 256)        bC = bq[n];
        else if (n < 512)   bC = bk[n-256] * 0.0625f;
        else if (n < 768)   bC = bv[n-512];
        else if (n < 1024)  bC = bg[n-768] + input_bias[n-768];
        else                bC = bg[n-768];
        biasC[n] = bC;
    }
}

// ---------------- fused projection GEMM: f16 single-pass, f16 plane outputs
__global__ __launch_bounds__(256, 4) void proj_gemm(
    const f16* __restrict__ xf, const f16* __restrict__ Wf,
    const float* __restrict__ biasC,
    f16* __restrict__ qP, f16* __restrict__ kP, f16* __restrict__ vP,
    f16* __restrict__ liP, f16* __restrict__ lfP, f16* __restrict__ soP)
{
    __shared__ f16 Af[128*32];
    __shared__ f16 Bf[128*32];
    const int tid = threadIdx.x;
    const int w = tid >> 6, l = tid & 63;
    const int wr = w >> 1, wc = w & 1;
    const int m0 = blockIdx.x * 128;
    const int n0 = blockIdx.y * 128;
    const int lr = l & 15, lk = l >> 4;

    f32x4 acc[4][4] = {};

    for (int kt = 0; kt < 256; kt += 32) {
        #pragma unroll
        for (int p = 0; p < 2; ++p) {
            int e = p*2048 + tid*8;
            int row = e >> 5;
            int cb  = (e >> 3) & 3;
            int scol = ((cb ^ ((row >> 1) & 3)) << 3);
            GLD16(xf + (size_t)(m0 + row)*256 + kt + scol, Af + e);
            GLD16(Wf + (size_t)(n0 + row)*256 + kt + scol, Bf + e);
        }
        __syncthreads();

        f16x8 af[4], bf[4];
        #pragma unroll
        for (int mi = 0; mi < 4; ++mi) {
            int row = wr*64 + mi*16 + lr;
            int slot = lk ^ ((row >> 1) & 3);
            af[mi] = *(const f16x8*)(Af + row*32 + slot*8);
        }
        #pragma unroll
        for (int ni = 0; ni < 4; ++ni) {
            int row = wc*64 + ni*16 + lr;
            int slot = lk ^ ((row >> 1) & 3);
            bf[ni] = *(const f16x8*)(Bf + row*32 + slot*8);
        }
        #pragma unroll
        for (int ni = 0; ni < 4; ++ni)
            #pragma unroll
            for (int mi = 0; mi < 4; ++mi)
                acc[mi][ni] = MFMA16(af[mi], bf[ni], acc[mi][ni]);
        __syncthreads();
    }

    const int seg = n0 >> 8;   // wg-uniform plane select
    f16* dst = (seg == 0) ? qP : (seg == 1) ? kP : (seg == 2) ? vP
             : (seg == 3) ? liP : (seg == 4) ? lfP : soP;
    #pragma unroll
    for (int mi = 0; mi < 4; ++mi) {
        #pragma unroll
        for (int ni = 0; ni < 4; ++ni) {
            int gcol = n0 + wc*64 + ni*16 + lr;
            int c = gcol & 255;
            float bC = biasC[gcol];
            #pragma unroll
            for (int r = 0; r < 4; ++r) {
                int grow = m0 + wr*64 + mi*16 + lk*4 + r;
                dst[(size_t)grow*256 + c] = (f16)(acc[mi][ni][r] + bC);
            }
        }
    }
}

// ---------------- fused chunk summary + Delta-M (bf16 split staging, bf16 DM):
__global__ __launch_bounds__(256) void s2_dm(
    const f16* __restrict__ kP, const f16* __restrict__ vP,
    const f16* __restrict__ liP, const f16* __restrict__ lfP,
    float* __restrict__ Csum, float* __restrict__ Mu, float* __restrict__ Bn,
    bf16* __restrict__ DM)
{
    __shared__ bf16 BTh[DMODEL][40], BTl[DMODEL][40];
    __shared__ bf16 KTh[DMODEL][40], KTl[DMODEL][40];
    const int tid = threadIdx.x;
    const int w = tid >> 6, l = tid & 63;
    const int b = blockIdx.x >> 6, c = blockIdx.x & 63;
    const size_t pb = ((size_t)b*T_LEN + (size_t)c*CH_L)*DMODEL;

    {
        float C = 0.f, mu = -3e38f;
        float val[CH_L];
        #pragma unroll
        for (int s = 0; s < CH_L; ++s) {
            size_t o = pb + (size_t)s*DMODEL + tid;
            C += nsoftplus_fast((float)lfP[o]);
            val[s] = 10.0f * tanh_fast(0.1f * (float)liP[o]) - C;
            mu = fmaxf(mu, val[s]);
        }
        float bn = 0.f;
        #pragma unroll
        for (int s = 0; s < CH_L; ++s) {
            size_t o = pb + (size_t)s*DMODEL + tid;
            float e = __expf(val[s] - mu);
            float kv = (float)kP[o];
            bn += e * kv;
            float bv = e * (float)vP[o];
            bf16 h, lo; split_bf16(bv, h, lo);
            BTh[tid][s] = h; BTl[tid][s] = lo;
            bf16 kh, kl; split_bf16(kv, kh, kl);
            KTh[tid][s] = kh; KTl[tid][s] = kl;
        }
        size_t so = ((size_t)b*NCH + c)*DMODEL + tid;
        Csum[so] = C; Mu[so] = mu; Bn[so] = bn;
    }
    __syncthreads();

    const int lr = l & 15, lk = l >> 4;
    bf16x8 Ah[4], Al[4];
    #pragma unroll
    for (int it = 0; it < 4; ++it) {
        int row = w*64 + it*16 + lr;
        Ah[it] = *(const bf16x8*)&BTh[row][lk*8];
        Al[it] = *(const bf16x8*)&BTl[row][lk*8];
    }
    bf16* DMc = DM + (size_t)((size_t)b*NCH + c)*MSLOT;
    #pragma unroll
    for (int jt = 0; jt < 16; ++jt) {
        int jcol = jt*16 + lr;
        bf16x8 bh = *(const bf16x8*)&KTh[jcol][lk*8];
        bf16x8 bl = *(const bf16x8*)&KTl[jcol][lk*8];
        #pragma unroll
        for (int it = 0; it < 4; ++it) {
            f32x4 a = {0.f,0.f,0.f,0.f};
            a = MFMA(Ah[it], bh, a);
            a = MFMA(Al[it], bh, a);
            a = MFMA(Ah[it], bl, a);
            #pragma unroll
            for (int r = 0; r < 4; ++r)
                DMc[(size_t)(w*64 + it*16 + lk*4 + r)*DMODEL + jcol] = (bf16)a[r];
        }
    }
}

// ---------------- sequential compose of (m,n) boundary states (batch-4 prefetched)
__global__ __launch_bounds__(256) void chunk_compose(
    const float* __restrict__ Csum, const float* __restrict__ Mu, const float* __restrict__ Bn,
    float* __restrict__ mIn, float* __restrict__ nIn, float* __restrict__ Th,
    float* __restrict__ Dd, float* __restrict__ Ee)
{
    const int b = blockIdx.x;
    const int j = threadIdx.x;
    float m = 0.f, n = 0.f;
    #pragma unroll 1
    for (int c = 0; c < NCH; c += 4) {
        size_t o0 = ((size_t)b*NCH + c)*DMODEL + j;
        float cs0 = Csum[o0],            mu0 = Mu[o0],            bn0 = Bn[o0];
        float cs1 = Csum[o0 + DMODEL],   mu1 = Mu[o0 + DMODEL],   bn1 = Bn[o0 + DMODEL];
        float cs2 = Csum[o0 + 2*DMODEL], mu2 = Mu[o0 + 2*DMODEL], bn2 = Bn[o0 + 2*DMODEL];
        float cs3 = Csum[o0 + 3*DMODEL], mu3 = Mu[o0 + 3*DMODEL], bn3 = Bn[o0 + 3*DMODEL];
        #define STEP(CS, MUv, BNv, OFF) { \
            mIn[o0 + (OFF)] = m; nIn[o0 + (OFF)] = n; \
            float th = fmaxf(m, MUv); \
            Th[o0 + (OFF)] = th; \
            float emu = __expf(MUv - th); \
            float d = __expf(m - th); \
            Dd[o0 + (OFF)] = d; Ee[o0 + (OFF)] = emu; \
            n = d*n + emu*(BNv); \
            m = (CS) + th; }
        STEP(cs0, mu0, bn0, 0)
        STEP(cs1, mu1, bn1, DMODEL)
        STEP(cs2, mu2, bn2, 2*DMODEL)
        STEP(cs3, mu3, bn3, 3*DMODEL)
        #undef STEP
    }
}

// ---------------- compose M across chunks; 512 threads = 2 i-rows per block
__global__ __launch_bounds__(512) void s3_compose(
    const float* __restrict__ Dd, const float* __restrict__ Ee, bf16* __restrict__ DM)
{
    const int b = blockIdx.x >> 7;
    const int i = ((blockIdx.x & 127) << 1) + (threadIdx.x >> 8);
    const int j = threadIdx.x & 255;
    float acc = 0.f;
    const size_t base = ((size_t)b*NCH)*MSLOT + (size_t)i*DMODEL + j;
    const size_t sb = (size_t)b*NCH*DMODEL + i;
    #pragma unroll 1
    for (int c = 0; c < NCH; c += 4) {
        float dm0 = (float)DM[base + (size_t)(c+0)*MSLOT];
        float dm1 = (float)DM[base + (size_t)(c+1)*MSLOT];
        float dm2 = (float)DM[base + (size_t)(c+2)*MSLOT];
        float dm3 = (float)DM[base + (size_t)(c+3)*MSLOT];
        float d0 = Dd[sb + (size_t)(c+0)*DMODEL], e0 = Ee[sb + (size_t)(c+0)*DMODEL];
        float d1 = Dd[sb + (size_t)(c+1)*DMODEL], e1 = Ee[sb + (size_t)(c+1)*DMODEL];
        float d2 = Dd[sb + (size_t)(c+2)*DMODEL], e2 = Ee[sb + (size_t)(c+2)*DMODEL];
        float d3 = Dd[sb + (size_t)(c+3)*DMODEL], e3 = Ee[sb + (size_t)(c+3)*DMODEL];
        if (c > 0) DM[base + (size_t)(c+0)*MSLOT] = (bf16)acc;
        acc = d0*acc + e0*dm0;
        DM[base + (size_t)(c+1)*MSLOT] = (bf16)acc;
        acc = d1*acc + e1*dm1;
        DM[base + (size_t)(c+2)*MSLOT] = (bf16)acc;
        acc = d2*acc + e2*dm2;
        DM[base + (size_t)(c+3)*MSLOT] = (bf16)acc;
        acc = d3*acc + e3*dm3;
    }
}

// ---------------- per-chunk output + fused RMSNorm (bf16 MFMA path, f16 plane inputs)
__global__ __launch_bounds__(256) void s4_chunk(
    const f16* __restrict__ qP, const f16* __restrict__ kP, const f16* __restrict__ vP,
    const f16* __restrict__ liP, const f16* __restrict__ lfP, const f16* __restrict__ soP,
    const float* __restrict__ mIn, const float* __restrict__ nIn, const float* __restrict__ Th,
    const bf16* __restrict__ DM, const float* __restrict__ norm_scale,
    float* __restrict__ out)
{
    __shared__ __align__(16) char kqbuf[33792];
    bf16 (*Kf)[264] = (bf16(*)[264])kqbuf;
    bf16 (*Qf)[264] = (bf16(*)[264])(kqbuf + 16896);
    float (*Hout)[264] = (float(*)[264])kqbuf;
    __shared__ bf16 F1L[CH_L][264];
    __shared__ __align__(16) bf16 BTh[DMODEL][40];
    __shared__ __align__(16) bf16 GT[CH_L][48];
    __shared__ float part[CH_L][4];
    __shared__ float denoms[CH_L];
    __shared__ float exL[DMODEL];

    const int tid = threadIdx.x;
    const int w = tid >> 6, l = tid & 63;
    const int b = blockIdx.x >> 6;
    const int c = blockIdx.x & 63;
    const size_t pb = ((size_t)b*T_LEN + (size_t)c*CH_L)*DMODEL;

    // phase 1: per-dim recurrences (thread = dim)
    const int i = tid;
    const size_t cbx = ((size_t)b*NCH + c)*DMODEL + i;
    const float thL = Th[cbx];
    const float mI = mIn[cbx];
    float P[CH_L];
    {
        float C = 0.f, mu = -3e38f, n = nIn[cbx], thp = mI;
        #pragma unroll
        for (int t = 0; t < CH_L; ++t) {
            size_t o = pb + (size_t)t*DMODEL + i;
            float lf = nsoftplus_fast((float)lfP[o]);
            float li = 10.0f * tanh_fast(0.1f * (float)liP[o]);
            float kv = (float)kP[o], qv = (float)qP[o], vv = (float)vP[o];
            C += lf;
            float vlc = li - C;
            mu = fmaxf(mu, vlc);
            float tht = fmaxf(mI, mu);
            float f = __expf(thp - tht);
            float iv = __expf(vlc - tht);
            n = f*n + iv*kv;
            thp = tht;
            P[t] = n * qv;
            Kf[t][i] = (bf16)kv;
            Qf[t][i] = (bf16)qv;
            F1L[t][i] = (bf16)__expf(mI - tht);
            BTh[i][t] = (bf16)(__expf(vlc - thL) * vv);
        }
        exL[i] = __expf(thL - mI);
    }
    // phase 2: wave-reduce P
    #pragma unroll
    for (int t = 0; t < CH_L; ++t) {
        float s = P[t];
        #pragma unroll
        for (int sh = 32; sh; sh >>= 1) s += __shfl_xor(s, sh);
        if (l == 0) part[t][w] = s;
    }
    __syncthreads();

    // phase 3a: denominators
    if (tid < CH_L)
        denoms[tid] = fmaxf(fabsf(part[tid][0] + part[tid][1] + part[tid][2] + part[tid][3]), 1e-6f);

    // phase 3b: G = K Q^T single-pass bf16
    {
        const int a = w & 1, bb = w >> 1;
        const int lr = l & 15, lk2 = l >> 4;
        if (a == 1 && bb == 0) {
            bf16x4 z = {(bf16)0.f, (bf16)0.f, (bf16)0.f, (bf16)0.f};
            *(bf16x4*)&GT[lr][16 + lk2*4] = z;
        } else {
            f32x4 g = {0.f,0.f,0.f,0.f};
            #pragma unroll
            for (int ks = 0; ks < 8; ++ks) {
                bf16x8 ah = *(const bf16x8*)&Kf[16*a  + lr][ks*32 + lk2*8];
                bf16x8 bh = *(const bf16x8*)&Qf[16*bb + lr][ks*32 + lk2*8];
                g = MFMA(ah, bh, g);
            }
            bf16x4 gv;
            #pragma unroll
            for (int r = 0; r < 4; ++r) {
                int s = 16*a + lk2*4 + r, t = 16*bb + lr;
                gv[r] = (s <= t) ? (bf16)g[r] : (bf16)0.f;
            }
            *(bf16x4*)&GT[16*bb + lr][16*a + lk2*4] = gv;
        }
    }
    __syncthreads();

    // phase 4: output GEMMs
    const int tt = w & 1;
    const int lr = l & 15, lk2 = l >> 4;
    const int trow = tt*16 + lr;
    f32x4 acc_a[8], acc_b[8];

    {
        bf16x8 gh = *(const bf16x8*)&GT[trow][lk2*8];
        #pragma unroll
        for (int it = 0; it < 8; ++it) {
            int irow = ((w>>1)*8 + it)*16 + lr;
            bf16x8 bb2 = *(const bf16x8*)&BTh[irow][lk2*8];
            f32x4 a = {0.f,0.f,0.f,0.f};
            acc_a[it] = MFMA(gh, bb2, a);
        }
    }
    #pragma unroll
    for (int it = 0; it < 8; ++it) acc_b[it] = (f32x4){0.f,0.f,0.f,0.f};
    if (c > 0) {
        const u16* Mbase = (const u16*)DM + (size_t)((size_t)b*NCH + c)*MSLOT;
        #pragma unroll
        for (int ks = 0; ks < 8; ++ks) {
            bf16x8 qh = *(const bf16x8*)&Qf[trow][ks*32 + lk2*8];
            #pragma unroll
            for (int it = 0; it < 8; ++it) {
                int irow = ((w>>1)*8 + it)*16 + lr;
                union { u16x8 u; bf16x8 h; } M8;
                M8.u = *(const u16x8*)(Mbase + (size_t)irow*DMODEL + ks*32 + lk2*8);
                acc_b[it] = MFMA(qh, M8.h, acc_b[it]);
            }
        }
    }
    __syncthreads();   // all Kf/Qf reads done; kqbuf becomes Hout

    // epilogue part 1
    #pragma unroll
    for (int it = 0; it < 8; ++it) {
        int icol = ((w>>1)*8 + it)*16 + lr;
        float ex = exL[icol];
        #pragma unroll
        for (int r = 0; r < 4; ++r) {
            int t = tt*16 + lk2*4 + r;
            float F1 = (float)F1L[t][icol];
            float h = F1 * (acc_b[it][r] + ex * acc_a[it][r]);
            size_t o = pb + (size_t)t*DMODEL + icol;
            Hout[t][icol] = sigmoid_fast((float)soP[o]) * h / denoms[t];
        }
    }
    __syncthreads();
    // epilogue part 2: fused RMSNorm
    #pragma unroll
    for (int r = 0; r < 8; ++r) {
        int t = w*8 + r;
        f32x4 hv = *(const f32x4*)&Hout[t][l*4];
        float ss = hv[0]*hv[0] + hv[1]*hv[1] + hv[2]*hv[2] + hv[3]*hv[3];
        #pragma unroll
        for (int sh = 32; sh; sh >>= 1) ss += __shfl_xor(ss, sh);
        float rinv = rsqrtf(ss * (1.0f/256.0f) + 1e-8f);
        f32x4 ns = *(const f32x4*)(norm_scale + l*4);
        f32x4 o4;
        #pragma unroll
        for (int e = 0; e < 4; ++e) o4[e] = hv[e] * rinv * ns[e];
        *(f32x4*)(out + pb + (size_t)t*DMODEL + l*4) = o4;
    }
}

extern "C" void kernel_launch(void* const* d_in, const int* in_sizes, int n_in,
                              void* d_out, int out_size, void* d_ws, size_t ws_size,
                              hipStream_t stream) {
    const float* x          = (const float*)d_in[0];
    const float* Wq         = (const float*)d_in[1];
    const float* bq         = (const float*)d_in[2];
    const float* Wk         = (const float*)d_in[3];
    const float* bk         = (const float*)d_in[4];
    const float* Wv         = (const float*)d_in[5];
    const float* bv         = (const float*)d_in[6];
    const float* Wg         = (const float*)d_in[7];
    const float* bg         = (const float*)d_in[8];
    const float* input_bias = (const float*)d_in[9];
    const float* norm_scale = (const float*)d_in[10];
    float* out = (float*)d_out;

    // f32 scratch
    float* Csum = (float*)d_ws;
    float* Mu   = Csum + SUMSZ;
    float* Bn   = Mu   + SUMSZ;
    float* mIn  = Bn   + SUMSZ;
    float* nIn  = mIn  + SUMSZ;
    float* Th   = nIn  + SUMSZ;
    float* Dd   = Th   + SUMSZ;
    float* Ee   = Dd   + SUMSZ;
    float* biasC = Ee  + SUMSZ;                        // 1536 floats (pad 2048)
    // f16/bf16 scratch
    f16*   qP   = (f16*)(biasC + 2048);
    f16*   kP   = qP  + PLANE;
    f16*   vP   = kP  + PLANE;
    f16*   liP  = vP  + PLANE;
    f16*   lfP  = liP + PLANE;
    f16*   soP  = lfP + PLANE;
    bf16*  DM   = (bf16*)(soP + PLANE);                // 4*64*65536 bf16 = 32 MiB
    f16*   Wf   = (f16*)(DM + (size_t)BATCH*NCH*MSLOT);
    f16*   xf   = Wf + 1536*256;

    pack_w<<<dim3(96), dim3(256), 0, stream>>>(Wq, Wk, Wv, Wg, bq, bk, bv, bg, input_bias,
                                               Wf, biasC);
    split_x<<<dim3(1024), dim3(256), 0, stream>>>(x, xf);
    proj_gemm<<<dim3(64, 12), dim3(256), 0, stream>>>(xf, Wf, biasC,
                                                      qP, kP, vP, liP, lfP, soP);
    s2_dm<<<dim3(BATCH*NCH), dim3(256), 0, stream>>>(kP, vP, liP, lfP, Csum, Mu, Bn, DM);
    chunk_compose<<<dim3(BATCH), dim3(256), 0, stream>>>(Csum, Mu, Bn, mIn, nIn, Th, Dd, Ee);
    s3_compose<<<dim3(BATCH*128), dim3(512), 0, stream>>>(Dd, Ee, DM);
    s4_chunk<<<dim3(BATCH*NCH), dim3(256), 0, stream>>>(qP, kP, vP, liP, lfP, soP,
                                                        mIn, nIn, Th, DM, norm_scale, out);
}

// Round 16
// 92.266 us; speedup vs baseline: 1.6973x; 1.0288x over previous
//
#include <hip/hip_runtime.h>
#include <hip/hip_bf16.h>
#include <math.h>

#define T_LEN 2048
#define BATCH 4
#define DMODEL 256
#define MROWS (BATCH*T_LEN)
#define PLANE (MROWS*DMODEL)
#define CH_L 32
#define NCH  (T_LEN/CH_L)          // 64
#define SUMSZ (BATCH*NCH*DMODEL)   // 65536
#define MSLOT (DMODEL*DMODEL)      // 65536

typedef __bf16 bf16;
typedef __bf16 bf16x4 __attribute__((ext_vector_type(4)));
typedef __bf16 bf16x8 __attribute__((ext_vector_type(8)));
typedef _Float16 f16;
typedef _Float16 f16x8 __attribute__((ext_vector_type(8)));
typedef float  f32x4  __attribute__((ext_vector_type(4)));
typedef unsigned short u16;
typedef u16 u16x8 __attribute__((ext_vector_type(8)));
typedef unsigned int u32;

#define MFMA(a,b,c)   __builtin_amdgcn_mfma_f32_16x16x32_bf16(a, b, c, 0, 0, 0)
#define MFMA16(a,b,c) __builtin_amdgcn_mfma_f32_16x16x32_f16(a, b, c, 0, 0, 0)

__device__ __forceinline__ void split_bf16(float x, bf16& hi, bf16& lo) {
    hi = (bf16)x;
    lo = (bf16)(x - (float)hi);
}

// fast transcendentals (hardware v_exp_f32 based)
__device__ __forceinline__ float tanh_fast(float z) {
    z = fminf(fmaxf(z, -15.f), 15.f);
    float e = __expf(2.f * z);
    return (e - 1.f) / (e + 1.f);
}
__device__ __forceinline__ float nsoftplus_fast(float y) {   // -softplus(y)
    return -(fmaxf(y, 0.f) + __logf(1.f + __expf(-fabsf(y))));
}
__device__ __forceinline__ float sigmoid_fast(float y) {
    return 1.f / (1.f + __expf(-y));
}

#define GLD16(SRC, DST) __builtin_amdgcn_global_load_lds( \
    (const __attribute__((address_space(1))) void*)(SRC), \
    (__attribute__((address_space(3))) void*)(DST), 16, 0, 0)

// ---------------- merged prep: blocks [0,1024) convert x->f16; blocks [1024,1120) pack W
__global__ __launch_bounds__(256) void prep(const float* __restrict__ x,
                                            const float* __restrict__ Wq,
                                            const float* __restrict__ Wk,
                                            const float* __restrict__ Wv,
                                            const float* __restrict__ Wg,
                                            const float* __restrict__ bq,
                                            const float* __restrict__ bk,
                                            const float* __restrict__ bv,
                                            const float* __restrict__ bg,
                                            const float* __restrict__ input_bias,
                                            f16* __restrict__ xf,
                                            f16* __restrict__ Wf,
                                            float* __restrict__ biasC) {
    __shared__ float tile[16][260];
    const int tid = threadIdx.x;
    if (blockIdx.x < 1024) {
        int i = (blockIdx.x*256 + tid) * 8;
        f32x4 a = *(const f32x4*)(x + i);
        f32x4 b = *(const f32x4*)(x + i + 4);
        f16x8 h;
        #pragma unroll
        for (int e = 0; e < 4; ++e) {
            h[e]   = (f16)a[e];
            h[4+e] = (f16)b[e];
        }
        *(f16x8*)(xf + i) = h;
        return;
    }
    const int n0 = (blockIdx.x - 1024) * 16;
    const float* src; int nb, nw;
    float scale = 1.0f;
    if (n0 < 256)      { src = Wq; nb = n0;       nw = 256; }
    else if (n0 < 512) { src = Wk; nb = n0 - 256; nw = 256; scale = 0.0625f; }
    else if (n0 < 768) { src = Wv; nb = n0 - 512; nw = 256; }
    else               { src = Wg; nb = n0 - 768; nw = 768; }
    const int j = tid & 15, kk = tid >> 4;
    #pragma unroll
    for (int r = 0; r < 16; ++r) {
        int k = r*16 + kk;
        tile[j][k] = src[(size_t)k*nw + nb + j] * scale;
    }
    __syncthreads();
    #pragma unroll
    for (int r = 0; r < 16; ++r)
        Wf[(size_t)(n0 + r)*256 + tid] = (f16)tile[r][tid];
    if (tid < 16) {
        int n = n0 + tid;
        float bC;
        if (n < 256)        bC = bq[n];
        else if (n < 512)   bC = bk[n-256] * 0.0625f;
        else if (n < 768)   bC = bv[n-512];
        else if (n < 1024)  bC = bg[n-768] + input_bias[n-768];
        else                bC = bg[n-768];
        biasC[n] = bC;
    }
}

// ---------------- fused projection GEMM: f16, BK=64 (half the barrier drains).
// 128x128 tile, 32KB LDS, 8-slot XOR swizzle both sides, uniform epilogue.
__global__ __launch_bounds__(256, 4) void proj_gemm(
    const f16* __restrict__ xf, const f16* __restrict__ Wf,
    const float* __restrict__ biasC,
    f16* __restrict__ qP, f16* __restrict__ kP, f16* __restrict__ vP,
    f16* __restrict__ liP, f16* __restrict__ lfP, f16* __restrict__ soP)
{
    __shared__ f16 Af[128*64];
    __shared__ f16 Bf[128*64];
    const int tid = threadIdx.x;
    const int w = tid >> 6, l = tid & 63;
    const int wr = w >> 1, wc = w & 1;
    const int m0 = blockIdx.x * 128;
    const int n0 = blockIdx.y * 128;
    const int lr = l & 15, lk = l >> 4;

    f32x4 acc[4][4] = {};

    for (int kt = 0; kt < 256; kt += 64) {
        #pragma unroll
        for (int p = 0; p < 4; ++p) {
            int e = p*2048 + tid*8;
            int row = e >> 6;
            int slot = (e >> 3) & 7;
            int scol = ((slot ^ (row & 7)) << 3);
            GLD16(xf + (size_t)(m0 + row)*256 + kt + scol, Af + e);
            GLD16(Wf + (size_t)(n0 + row)*256 + kt + scol, Bf + e);
        }
        __syncthreads();

        #pragma unroll
        for (int ksub = 0; ksub < 2; ++ksub) {
            f16x8 af[4], bf[4];
            #pragma unroll
            for (int mi = 0; mi < 4; ++mi) {
                int row = wr*64 + mi*16 + lr;
                int slot = (ksub*4 + lk) ^ (row & 7);
                af[mi] = *(const f16x8*)(Af + row*64 + slot*8);
            }
            #pragma unroll
            for (int ni = 0; ni < 4; ++ni) {
                int row = wc*64 + ni*16 + lr;
                int slot = (ksub*4 + lk) ^ (row & 7);
                bf[ni] = *(const f16x8*)(Bf + row*64 + slot*8);
            }
            #pragma unroll
            for (int ni = 0; ni < 4; ++ni)
                #pragma unroll
                for (int mi = 0; mi < 4; ++mi)
                    acc[mi][ni] = MFMA16(af[mi], bf[ni], acc[mi][ni]);
        }
        __syncthreads();
    }

    const int seg = n0 >> 8;   // wg-uniform plane select
    f16* dst = (seg == 0) ? qP : (seg == 1) ? kP : (seg == 2) ? vP
             : (seg == 3) ? liP : (seg == 4) ? lfP : soP;
    #pragma unroll
    for (int mi = 0; mi < 4; ++mi) {
        #pragma unroll
        for (int ni = 0; ni < 4; ++ni) {
            int gcol = n0 + wc*64 + ni*16 + lr;
            int c = gcol & 255;
            float bC = biasC[gcol];
            #pragma unroll
            for (int r = 0; r < 4; ++r) {
                int grow = m0 + wr*64 + mi*16 + lk*4 + r;
                dst[(size_t)grow*256 + c] = (f16)(acc[mi][ni][r] + bC);
            }
        }
    }
}

// ---------------- fused chunk summary + Delta-M (bf16 split staging, bf16 DM):
__global__ __launch_bounds__(256) void s2_dm(
    const f16* __restrict__ kP, const f16* __restrict__ vP,
    const f16* __restrict__ liP, const f16* __restrict__ lfP,
    float* __restrict__ Csum, float* __restrict__ Mu, float* __restrict__ Bn,
    bf16* __restrict__ DM)
{
    __shared__ bf16 BTh[DMODEL][40], BTl[DMODEL][40];
    __shared__ bf16 KTh[DMODEL][40], KTl[DMODEL][40];
    const int tid = threadIdx.x;
    const int w = tid >> 6, l = tid & 63;
    const int b = blockIdx.x >> 6, c = blockIdx.x & 63;
    const size_t pb = ((size_t)b*T_LEN + (size_t)c*CH_L)*DMODEL;

    {
        float C = 0.f, mu = -3e38f;
        float val[CH_L];
        #pragma unroll
        for (int s = 0; s < CH_L; ++s) {
            size_t o = pb + (size_t)s*DMODEL + tid;
            C += nsoftplus_fast((float)lfP[o]);
            val[s] = 10.0f * tanh_fast(0.1f * (float)liP[o]) - C;
            mu = fmaxf(mu, val[s]);
        }
        float bn = 0.f;
        #pragma unroll
        for (int s = 0; s < CH_L; ++s) {
            size_t o = pb + (size_t)s*DMODEL + tid;
            float e = __expf(val[s] - mu);
            float kv = (float)kP[o];
            bn += e * kv;
            float bv = e * (float)vP[o];
            bf16 h, lo; split_bf16(bv, h, lo);
            BTh[tid][s] = h; BTl[tid][s] = lo;
            bf16 kh, kl; split_bf16(kv, kh, kl);
            KTh[tid][s] = kh; KTl[tid][s] = kl;
        }
        size_t so = ((size_t)b*NCH + c)*DMODEL + tid;
        Csum[so] = C; Mu[so] = mu; Bn[so] = bn;
    }
    __syncthreads();

    const int lr = l & 15, lk = l >> 4;
    bf16x8 Ah[4], Al[4];
    #pragma unroll
    for (int it = 0; it < 4; ++it) {
        int row = w*64 + it*16 + lr;
        Ah[it] = *(const bf16x8*)&BTh[row][lk*8];
        Al[it] = *(const bf16x8*)&BTl[row][lk*8];
    }
    bf16* DMc = DM + (size_t)((size_t)b*NCH + c)*MSLOT;
    #pragma unroll
    for (int jt = 0; jt < 16; ++jt) {
        int jcol = jt*16 + lr;
        bf16x8 bh = *(const bf16x8*)&KTh[jcol][lk*8];
        bf16x8 bl = *(const bf16x8*)&KTl[jcol][lk*8];
        #pragma unroll
        for (int it = 0; it < 4; ++it) {
            f32x4 a = {0.f,0.f,0.f,0.f};
            a = MFMA(Ah[it], bh, a);
            a = MFMA(Al[it], bh, a);
            a = MFMA(Ah[it], bl, a);
            #pragma unroll
            for (int r = 0; r < 4; ++r)
                DMc[(size_t)(w*64 + it*16 + lk*4 + r)*DMODEL + jcol] = (bf16)a[r];
        }
    }
}

// ---------------- sequential compose of (m,n) boundary states (batch-4 prefetched)
__global__ __launch_bounds__(256) void chunk_compose(
    const float* __restrict__ Csum, const float* __restrict__ Mu, const float* __restrict__ Bn,
    float* __restrict__ mIn, float* __restrict__ nIn, float* __restrict__ Th,
    float* __restrict__ Dd, float* __restrict__ Ee)
{
    const int b = blockIdx.x;
    const int j = threadIdx.x;
    float m = 0.f, n = 0.f;
    #pragma unroll 1
    for (int c = 0; c < NCH; c += 4) {
        size_t o0 = ((size_t)b*NCH + c)*DMODEL + j;
        float cs0 = Csum[o0],            mu0 = Mu[o0],            bn0 = Bn[o0];
        float cs1 = Csum[o0 + DMODEL],   mu1 = Mu[o0 + DMODEL],   bn1 = Bn[o0 + DMODEL];
        float cs2 = Csum[o0 + 2*DMODEL], mu2 = Mu[o0 + 2*DMODEL], bn2 = Bn[o0 + 2*DMODEL];
        float cs3 = Csum[o0 + 3*DMODEL], mu3 = Mu[o0 + 3*DMODEL], bn3 = Bn[o0 + 3*DMODEL];
        #define STEP(CS, MUv, BNv, OFF) { \
            mIn[o0 + (OFF)] = m; nIn[o0 + (OFF)] = n; \
            float th = fmaxf(m, MUv); \
            Th[o0 + (OFF)] = th; \
            float emu = __expf(MUv - th); \
            float d = __expf(m - th); \
            Dd[o0 + (OFF)] = d; Ee[o0 + (OFF)] = emu; \
            n = d*n + emu*(BNv); \
            m = (CS) + th; }
        STEP(cs0, mu0, bn0, 0)
        STEP(cs1, mu1, bn1, DMODEL)
        STEP(cs2, mu2, bn2, 2*DMODEL)
        STEP(cs3, mu3, bn3, 3*DMODEL)
        #undef STEP
    }
}

// ---------------- compose M across chunks; 512 threads = 2 i-rows per block
__global__ __launch_bounds__(512) void s3_compose(
    const float* __restrict__ Dd, const float* __restrict__ Ee, bf16* __restrict__ DM)
{
    const int b = blockIdx.x >> 7;
    const int i = ((blockIdx.x & 127) << 1) + (threadIdx.x >> 8);
    const int j = threadIdx.x & 255;
    float acc = 0.f;
    const size_t base = ((size_t)b*NCH)*MSLOT + (size_t)i*DMODEL + j;
    const size_t sb = (size_t)b*NCH*DMODEL + i;
    #pragma unroll 1
    for (int c = 0; c < NCH; c += 4) {
        float dm0 = (float)DM[base + (size_t)(c+0)*MSLOT];
        float dm1 = (float)DM[base + (size_t)(c+1)*MSLOT];
        float dm2 = (float)DM[base + (size_t)(c+2)*MSLOT];
        float dm3 = (float)DM[base + (size_t)(c+3)*MSLOT];
        float d0 = Dd[sb + (size_t)(c+0)*DMODEL], e0 = Ee[sb + (size_t)(c+0)*DMODEL];
        float d1 = Dd[sb + (size_t)(c+1)*DMODEL], e1 = Ee[sb + (size_t)(c+1)*DMODEL];
        float d2 = Dd[sb + (size_t)(c+2)*DMODEL], e2 = Ee[sb + (size_t)(c+2)*DMODEL];
        float d3 = Dd[sb + (size_t)(c+3)*DMODEL], e3 = Ee[sb + (size_t)(c+3)*DMODEL];
        if (c > 0) DM[base + (size_t)(c+0)*MSLOT] = (bf16)acc;
        acc = d0*acc + e0*dm0;
        DM[base + (size_t)(c+1)*MSLOT] = (bf16)acc;
        acc = d1*acc + e1*dm1;
        DM[base + (size_t)(c+2)*MSLOT] = (bf16)acc;
        acc = d2*acc + e2*dm2;
        DM[base + (size_t)(c+3)*MSLOT] = (bf16)acc;
        acc = d3*acc + e3*dm3;
    }
}

// ---------------- per-chunk output + fused RMSNorm (bf16 MFMA path, f16 plane inputs)
__global__ __launch_bounds__(256) void s4_chunk(
    const f16* __restrict__ qP, const f16* __restrict__ kP, const f16* __restrict__ vP,
    const f16* __restrict__ liP, const f16* __restrict__ lfP, const f16* __restrict__ soP,
    const float* __restrict__ mIn, const float* __restrict__ nIn, const float* __restrict__ Th,
    const bf16* __restrict__ DM, const float* __restrict__ norm_scale,
    float* __restrict__ out)
{
    __shared__ __align__(16) char kqbuf[33792];
    bf16 (*Kf)[264] = (bf16(*)[264])kqbuf;
    bf16 (*Qf)[264] = (bf16(*)[264])(kqbuf + 16896);
    float (*Hout)[264] = (float(*)[264])kqbuf;
    __shared__ bf16 F1L[CH_L][264];
    __shared__ __align__(16) bf16 BTh[DMODEL][40];
    __shared__ __align__(16) bf16 GT[CH_L][48];
    __shared__ float part[CH_L][4];
    __shared__ float denoms[CH_L];
    __shared__ float exL[DMODEL];

    const int tid = threadIdx.x;
    const int w = tid >> 6, l = tid & 63;
    const int b = blockIdx.x >> 6;
    const int c = blockIdx.x & 63;
    const size_t pb = ((size_t)b*T_LEN + (size_t)c*CH_L)*DMODEL;

    // phase 1: per-dim recurrences (thread = dim)
    const int i = tid;
    const size_t cbx = ((size_t)b*NCH + c)*DMODEL + i;
    const float thL = Th[cbx];
    const float mI = mIn[cbx];
    float P[CH_L];
    {
        float C = 0.f, mu = -3e38f, n = nIn[cbx], thp = mI;
        #pragma unroll
        for (int t = 0; t < CH_L; ++t) {
            size_t o = pb + (size_t)t*DMODEL + i;
            float lf = nsoftplus_fast((float)lfP[o]);
            float li = 10.0f * tanh_fast(0.1f * (float)liP[o]);
            float kv = (float)kP[o], qv = (float)qP[o], vv = (float)vP[o];
            C += lf;
            float vlc = li - C;
            mu = fmaxf(mu, vlc);
            float tht = fmaxf(mI, mu);
            float f = __expf(thp - tht);
            float iv = __expf(vlc - tht);
            n = f*n + iv*kv;
            thp = tht;
            P[t] = n * qv;
            Kf[t][i] = (bf16)kv;
            Qf[t][i] = (bf16)qv;
            F1L[t][i] = (bf16)__expf(mI - tht);
            BTh[i][t] = (bf16)(__expf(vlc - thL) * vv);
        }
        exL[i] = __expf(thL - mI);
    }
    // phase 2: wave-reduce P
    #pragma unroll
    for (int t = 0; t < CH_L; ++t) {
        float s = P[t];
        #pragma unroll
        for (int sh = 32; sh; sh >>= 1) s += __shfl_xor(s, sh);
        if (l == 0) part[t][w] = s;
    }
    __syncthreads();

    // phase 3a: denominators
    if (tid < CH_L)
        denoms[tid] = fmaxf(fabsf(part[tid][0] + part[tid][1] + part[tid][2] + part[tid][3]), 1e-6f);

    // phase 3b: G = K Q^T single-pass bf16
    {
        const int a = w & 1, bb = w >> 1;
        const int lr = l & 15, lk2 = l >> 4;
        if (a == 1 && bb == 0) {
            bf16x4 z = {(bf16)0.f, (bf16)0.f, (bf16)0.f, (bf16)0.f};
            *(bf16x4*)&GT[lr][16 + lk2*4] = z;
        } else {
            f32x4 g = {0.f,0.f,0.f,0.f};
            #pragma unroll
            for (int ks = 0; ks < 8; ++ks) {
                bf16x8 ah = *(const bf16x8*)&Kf[16*a  + lr][ks*32 + lk2*8];
                bf16x8 bh = *(const bf16x8*)&Qf[16*bb + lr][ks*32 + lk2*8];
                g = MFMA(ah, bh, g);
            }
            bf16x4 gv;
            #pragma unroll
            for (int r = 0; r < 4; ++r) {
                int s = 16*a + lk2*4 + r, t = 16*bb + lr;
                gv[r] = (s <= t) ? (bf16)g[r] : (bf16)0.f;
            }
            *(bf16x4*)&GT[16*bb + lr][16*a + lk2*4] = gv;
        }
    }
    __syncthreads();

    // phase 4: output GEMMs
    const int tt = w & 1;
    const int lr = l & 15, lk2 = l >> 4;
    const int trow = tt*16 + lr;
    f32x4 acc_a[8], acc_b[8];

    {
        bf16x8 gh = *(const bf16x8*)&GT[trow][lk2*8];
        #pragma unroll
        for (int it = 0; it < 8; ++it) {
            int irow = ((w>>1)*8 + it)*16 + lr;
            bf16x8 bb2 = *(const bf16x8*)&BTh[irow][lk2*8];
            f32x4 a = {0.f,0.f,0.f,0.f};
            acc_a[it] = MFMA(gh, bb2, a);
        }
    }
    #pragma unroll
    for (int it = 0; it < 8; ++it) acc_b[it] = (f32x4){0.f,0.f,0.f,0.f};
    if (c > 0) {
        const u16* Mbase = (const u16*)DM + (size_t)((size_t)b*NCH + c)*MSLOT;
        #pragma unroll
        for (int ks = 0; ks < 8; ++ks) {
            bf16x8 qh = *(const bf16x8*)&Qf[trow][ks*32 + lk2*8];
            #pragma unroll
            for (int it = 0; it < 8; ++it) {
                int irow = ((w>>1)*8 + it)*16 + lr;
                union { u16x8 u; bf16x8 h; } M8;
                M8.u = *(const u16x8*)(Mbase + (size_t)irow*DMODEL + ks*32 + lk2*8);
                acc_b[it] = MFMA(qh, M8.h, acc_b[it]);
            }
        }
    }
    __syncthreads();   // all Kf/Qf reads done; kqbuf becomes Hout

    // epilogue part 1
    #pragma unroll
    for (int it = 0; it < 8; ++it) {
        int icol = ((w>>1)*8 + it)*16 + lr;
        float ex = exL[icol];
        #pragma unroll
        for (int r = 0; r < 4; ++r) {
            int t = tt*16 + lk2*4 + r;
            float F1 = (float)F1L[t][icol];
            float h = F1 * (acc_b[it][r] + ex * acc_a[it][r]);
            size_t o = pb + (size_t)t*DMODEL + icol;
            Hout[t][icol] = sigmoid_fast((float)soP[o]) * h / denoms[t];
        }
    }
    __syncthreads();
    // epilogue part 2: fused RMSNorm
    #pragma unroll
    for (int r = 0; r < 8; ++r) {
        int t = w*8 + r;
        f32x4 hv = *(const f32x4*)&Hout[t][l*4];
        float ss = hv[0]*hv[0] + hv[1]*hv[1] + hv[2]*hv[2] + hv[3]*hv[3];
        #pragma unroll
        for (int sh = 32; sh; sh >>= 1) ss += __shfl_xor(ss, sh);
        float rinv = rsqrtf(ss * (1.0f/256.0f) + 1e-8f);
        f32x4 ns = *(const f32x4*)(norm_scale + l*4);
        f32x4 o4;
        #pragma unroll
        for (int e = 0; e < 4; ++e) o4[e] = hv[e] * rinv * ns[e];
        *(f32x4*)(out + pb + (size_t)t*DMODEL + l*4) = o4;
    }
}

extern "C" void kernel_launch(void* const* d_in, const int* in_sizes, int n_in,
                              void* d_out, int out_size, void* d_ws, size_t ws_size,
                              hipStream_t stream) {
    const float* x          = (const float*)d_in[0];
    const float* Wq         = (const float*)d_in[1];
    const float* bq         = (const float*)d_in[2];
    const float* Wk         = (const float*)d_in[3];
    const float* bk         = (const float*)d_in[4];
    const float* Wv         = (const float*)d_in[5];
    const float* bv         = (const float*)d_in[6];
    const float* Wg         = (const float*)d_in[7];
    const float* bg         = (const float*)d_in[8];
    const float* input_bias = (const float*)d_in[9];
    const float* norm_scale = (const float*)d_in[10];
    float* out = (float*)d_out;

    // f32 scratch
    float* Csum = (float*)d_ws;
    float* Mu   = Csum + SUMSZ;
    float* Bn   = Mu   + SUMSZ;
    float* mIn  = Bn   + SUMSZ;
    float* nIn  = mIn  + SUMSZ;
    float* Th   = nIn  + SUMSZ;
    float* Dd   = Th   + SUMSZ;
    float* Ee   = Dd   + SUMSZ;
    float* biasC = Ee  + SUMSZ;                        // 1536 floats (pad 2048)
    // f16/bf16 scratch
    f16*   qP   = (f16*)(biasC + 2048);
    f16*   kP   = qP  + PLANE;
    f16*   vP   = kP  + PLANE;
    f16*   liP  = vP  + PLANE;
    f16*   lfP  = liP + PLANE;
    f16*   soP  = lfP + PLANE;
    bf16*  DM   = (bf16*)(soP + PLANE);                // 4*64*65536 bf16 = 32 MiB
    f16*   Wf   = (f16*)(DM + (size_t)BATCH*NCH*MSLOT);
    f16*   xf   = Wf + 1536*256;

    prep<<<dim3(1120), dim3(256), 0, stream>>>(x, Wq, Wk, Wv, Wg, bq, bk, bv, bg, input_bias,
                                               xf, Wf, biasC);
    proj_gemm<<<dim3(64, 12), dim3(256), 0, stream>>>(xf, Wf, biasC,
                                                      qP, kP, vP, liP, lfP, soP);
    s2_dm<<<dim3(BATCH*NCH), dim3(256), 0, stream>>>(kP, vP, liP, lfP, Csum, Mu, Bn, DM);
    chunk_compose<<<dim3(BATCH), dim3(256), 0, stream>>>(Csum, Mu, Bn, mIn, nIn, Th, Dd, Ee);
    s3_compose<<<dim3(BATCH*128), dim3(512), 0, stream>>>(Dd, Ee, DM);
    s4_chunk<<<dim3(BATCH*NCH), dim3(256), 0, stream>>>(qP, kP, vP, liP, lfP, soP,
                                                        mIn, nIn, Th, DM, norm_scale, out);
}